// Round 5
// baseline (134.701 us; speedup 1.0000x reference)
//
#include <hip/hip_runtime.h>

#define LOG2E 1.4426950408889634f

typedef float f32x4 __attribute__((ext_vector_type(4)));
typedef short s16x8 __attribute__((ext_vector_type(8)));
typedef __bf16 bf16x8 __attribute__((ext_vector_type(8)));
typedef unsigned int u32x2 __attribute__((ext_vector_type(2)));

union ABF { s16x8 s; bf16x8 v; };
union PKU { unsigned int u[4]; s16x8 s; bf16x8 v; };

__device__ __forceinline__ unsigned short f2bf(float f) {
  unsigned int u = __builtin_bit_cast(unsigned int, f);
  u += 0x7fffu + ((u >> 16) & 1u);
  return (unsigned short)(u >> 16);
}

__device__ __forceinline__ unsigned int cvt_pk_bf16(float a, float b) {
  unsigned int r;
  asm("v_cvt_pk_bf16_f32 %0, %1, %2" : "=v"(r) : "v"(a), "v"(b));
  return r;  // low16 = bf16(a), high16 = bf16(b)
}

// ---------------- k_pre: all converts + conv-weight repack + conf + gather ----------------

__global__ __launch_bounds__(256) void k_pre(const float* __restrict__ q_w,
                                             const float* __restrict__ kv_w,
                                             const float* __restrict__ proj_w,
                                             const float* __restrict__ sr_w,
                                             const float* __restrict__ token_score,
                                             const int* __restrict__ idx_token,
                                             const float* __restrict__ kv_x,
                                             unsigned short* __restrict__ q_wb,
                                             unsigned short* __restrict__ kv_wb,
                                             unsigned short* __restrict__ p_wb,
                                             unsigned short* __restrict__ w4t,
                                             float* __restrict__ conf,
                                             unsigned short* __restrict__ x4) {
  int bid = blockIdx.x, t = threadIdx.x;
  if (bid < 256) { int i = bid * 256 + t; q_wb[i] = f2bf(q_w[i]); return; }
  if (bid < 768) { int i = (bid - 256) * 256 + t; kv_wb[i] = f2bf(kv_w[i]); return; }
  if (bid < 1024) { int i = (bid - 768) * 256 + t; p_wb[i] = f2bf(proj_w[i]); return; }
  if (bid < 2048) {
    // w4t[co][k], k = (dh*2+dw)*256 + ci ; from sr_w[co][ci][dh][dw]
    int idx = (bid - 1024) * 256 + t;
    int co = idx >> 10, k = idx & 1023;
    int slot = k >> 8, ci = k & 255;
    int dh = slot >> 1, dw = slot & 1;
    w4t[idx] = f2bf(sr_w[((co * 256 + ci) * 2 + dh) * 2 + dw]);
    return;
  }
  if (bid < 2080) {
    // conf[b][m] = log2e * mean_{2x2}(token_score gathered) / 1.000001
    int i = (bid - 2048) * 256 + t;  // B*1024 = 8192
    int b = i >> 10, m = i & 1023;
    int h = m >> 5, w = m & 31;
    float s = 0.f;
#pragma unroll
    for (int dh = 0; dh < 2; ++dh)
#pragma unroll
      for (int dw = 0; dw < 2; ++dw) {
        int j = (2 * h + dh) * 64 + (2 * w + dw);
        s += token_score[b * 2048 + idx_token[b * 4096 + j]];
      }
    conf[i] = s * 0.25f * (1.0f / 1.000001f) * LOG2E;
    return;
  }
  // gather: x4 rearranged for conv-as-GEMM; 4 tokens/block, f32x4 vectorized
  int gi = (bid - 2080) * 4 + (t >> 6);  // 0..32767
  int c4i = t & 63;
  int b = gi >> 12, i = gi & 4095;
  int tok = idx_token[gi];
  int y = i >> 6, x = i & 63;
  int row = ((y >> 1) << 5) + (x >> 1);
  int slot = ((y & 1) << 1) + (x & 1);
  const float inv1 = 1.0f / 1.000001f;
  f32x4 v = *(const f32x4*)(kv_x + (size_t)(b * 2048 + tok) * 256 + c4i * 4);
  u32x2 w;
  w.x = cvt_pk_bf16(v[0] * inv1, v[1] * inv1);
  w.y = cvt_pk_bf16(v[2] * inv1, v[3] * inv1);
  *(u32x2*)(x4 + (size_t)((b * 1024 + row) * 4 + slot) * 256 + c4i * 4) = w;
}

// ---------------- k_qc: conv+LN (bid<512, 16 rows) + q-projection (bid>=512, 32 rows) ----------------
// Explicit register prefetch of the next K-step; launch_bounds(256,2) for pipelining headroom.

__global__ __launch_bounds__(256, 2) void k_qc(const float* __restrict__ q_x,
                                               const unsigned short* __restrict__ q_wb,
                                               unsigned short* __restrict__ q_s,
                                               const unsigned short* __restrict__ x4,
                                               const unsigned short* __restrict__ w4t,
                                               const float* __restrict__ sr_b,
                                               const float* __restrict__ ln_w,
                                               const float* __restrict__ ln_b,
                                               unsigned short* __restrict__ kv_ln) {
  __shared__ float srow[16][260];
  int tid = threadIdx.x;
  int wid = tid >> 6, lane = tid & 63, lg = lane >> 4, lc = lane & 15;
  int bid = blockIdx.x;

  if (bid < 512) {
    // ---- conv-as-GEMM + LayerNorm: 16 rows, K=1024 (32 steps), full prefetch ----
    int rowbase = bid * 16;
    f32x4 acc[4] = {};
    const unsigned short* ap = x4 + (size_t)(rowbase + lc) * 1024 + lg * 8;
    const unsigned short* bp = w4t + (size_t)(wid * 64 + lc) * 1024 + lg * 8;
    s16x8 ca, cb0, cb1, cb2, cb3;
    ca  = *(const s16x8*)(ap);
    cb0 = *(const s16x8*)(bp);
    cb1 = *(const s16x8*)(bp + 16 * 1024);
    cb2 = *(const s16x8*)(bp + 32 * 1024);
    cb3 = *(const s16x8*)(bp + 48 * 1024);
#pragma unroll
    for (int kc = 0; kc < 32; ++kc) {
      s16x8 na, nb0, nb1, nb2, nb3;
      if (kc < 31) {
        na  = *(const s16x8*)(ap + (kc + 1) * 32);
        nb0 = *(const s16x8*)(bp + (kc + 1) * 32);
        nb1 = *(const s16x8*)(bp + 16 * 1024 + (kc + 1) * 32);
        nb2 = *(const s16x8*)(bp + 32 * 1024 + (kc + 1) * 32);
        nb3 = *(const s16x8*)(bp + 48 * 1024 + (kc + 1) * 32);
      }
      ABF a, b;
      a.s = ca;
      b.s = cb0; acc[0] = __builtin_amdgcn_mfma_f32_16x16x32_bf16(a.v, b.v, acc[0], 0, 0, 0);
      b.s = cb1; acc[1] = __builtin_amdgcn_mfma_f32_16x16x32_bf16(a.v, b.v, acc[1], 0, 0, 0);
      b.s = cb2; acc[2] = __builtin_amdgcn_mfma_f32_16x16x32_bf16(a.v, b.v, acc[2], 0, 0, 0);
      b.s = cb3; acc[3] = __builtin_amdgcn_mfma_f32_16x16x32_bf16(a.v, b.v, acc[3], 0, 0, 0);
      if (kc < 31) { ca = na; cb0 = nb0; cb1 = nb1; cb2 = nb2; cb3 = nb3; }
    }
#pragma unroll
    for (int t = 0; t < 4; ++t) {
      int col = wid * 64 + t * 16 + lc;
      float bias = sr_b[col];
#pragma unroll
      for (int r = 0; r < 4; ++r) srow[lg * 4 + r][col] = acc[t][r] + bias;
    }
    __syncthreads();
    int r = tid >> 4, c16 = tid & 15;
    float vals[16];
    float sm = 0.f, ss = 0.f;
#pragma unroll
    for (int i = 0; i < 16; ++i) {
      float v = srow[r][c16 * 16 + i];
      vals[i] = v; sm += v; ss += v * v;
    }
#pragma unroll
    for (int m = 1; m < 16; m <<= 1) {
      sm += __shfl_xor(sm, m, 64);
      ss += __shfl_xor(ss, m, 64);
    }
    float mu = sm * (1.0f / 256.0f);
    float var = ss * (1.0f / 256.0f) - mu * mu;
    float rstd = rsqrtf(var + 1e-5f);
    s16x8 o0, o1;
#pragma unroll
    for (int i = 0; i < 8; ++i) {
      int c = c16 * 16 + i;
      o0[i] = (short)f2bf((vals[i] - mu) * rstd * ln_w[c] + ln_b[c]);
    }
#pragma unroll
    for (int i = 0; i < 8; ++i) {
      int c = c16 * 16 + 8 + i;
      o1[i] = (short)f2bf((vals[8 + i] - mu) * rstd * ln_w[c] + ln_b[c]);
    }
    *(s16x8*)(kv_ln + (size_t)(rowbase + r) * 256 + c16 * 16) = o0;
    *(s16x8*)(kv_ln + (size_t)(rowbase + r) * 256 + c16 * 16 + 8) = o1;
    return;
  }

  // ---- q projection: 32 rows, K=256 (8 steps), A-prefetch ----
  int rowbase = (bid - 512) * 32;
  f32x4 acc[2][4] = {};
  const float* ap0 = q_x + (size_t)(rowbase + lc) * 256 + lg * 8;
  const float* ap1 = ap0 + 16 * 256;
  const unsigned short* bp = q_wb + (size_t)(wid * 64 + lc) * 256 + lg * 8;
  f32x4 ca00 = *(const f32x4*)(ap0), ca01 = *(const f32x4*)(ap0 + 4);
  f32x4 ca10 = *(const f32x4*)(ap1), ca11 = *(const f32x4*)(ap1 + 4);
#pragma unroll
  for (int kc = 0; kc < 8; ++kc) {
    f32x4 na00, na01, na10, na11;
    if (kc < 7) {
      na00 = *(const f32x4*)(ap0 + (kc + 1) * 32);
      na01 = *(const f32x4*)(ap0 + (kc + 1) * 32 + 4);
      na10 = *(const f32x4*)(ap1 + (kc + 1) * 32);
      na11 = *(const f32x4*)(ap1 + (kc + 1) * 32 + 4);
    }
    PKU a0, a1;
    a0.u[0] = cvt_pk_bf16(ca00[0], ca00[1]);
    a0.u[1] = cvt_pk_bf16(ca00[2], ca00[3]);
    a0.u[2] = cvt_pk_bf16(ca01[0], ca01[1]);
    a0.u[3] = cvt_pk_bf16(ca01[2], ca01[3]);
    a1.u[0] = cvt_pk_bf16(ca10[0], ca10[1]);
    a1.u[1] = cvt_pk_bf16(ca10[2], ca10[3]);
    a1.u[2] = cvt_pk_bf16(ca11[0], ca11[1]);
    a1.u[3] = cvt_pk_bf16(ca11[2], ca11[3]);
#pragma unroll
    for (int t = 0; t < 4; ++t) {
      ABF bb; bb.s = *(const s16x8*)(bp + t * 4096 + kc * 32);
      acc[0][t] = __builtin_amdgcn_mfma_f32_16x16x32_bf16(a0.v, bb.v, acc[0][t], 0, 0, 0);
      acc[1][t] = __builtin_amdgcn_mfma_f32_16x16x32_bf16(a1.v, bb.v, acc[1][t], 0, 0, 0);
    }
    if (kc < 7) { ca00 = na00; ca01 = na01; ca10 = na10; ca11 = na11; }
  }
  const float qs = 0.17677669529663687f * LOG2E;
#pragma unroll
  for (int s = 0; s < 2; ++s)
#pragma unroll
    for (int t = 0; t < 4; ++t) {
      int col = wid * 64 + t * 16 + lc;
      int h = col >> 5, d = col & 31;
#pragma unroll
      for (int r = 0; r < 4; ++r) {
        int row = rowbase + s * 16 + lg * 4 + r;
        int b = row >> 11, n = row & 2047;
        q_s[(size_t)((b * 8 + h) * 2048 + n) * 32 + d] = f2bf(acc[s][t][r] * qs);
      }
    }
}

// ---------------- kv projection (8192x512, K=256), 16 rows/block, full prefetch ----------------

__global__ __launch_bounds__(256, 2) void k_kvproj(const unsigned short* __restrict__ kv_ln,
                                                   const unsigned short* __restrict__ wb,
                                                   unsigned short* __restrict__ kmat,
                                                   unsigned short* __restrict__ vt) {
  int tid = threadIdx.x;
  int wid = tid >> 6, lane = tid & 63, lg = lane >> 4, lc = lane & 15;
  int rowbase = blockIdx.x * 16;
  f32x4 acc[8] = {};
  const unsigned short* ap = kv_ln + (size_t)(rowbase + lc) * 256 + lg * 8;
  const unsigned short* bp = wb + (size_t)(wid * 128 + lc) * 256 + lg * 8;
  s16x8 ca, cb[8];
  ca = *(const s16x8*)(ap);
#pragma unroll
  for (int t = 0; t < 8; ++t) cb[t] = *(const s16x8*)(bp + t * 4096);
#pragma unroll
  for (int kc = 0; kc < 8; ++kc) {
    s16x8 na, nb[8];
    if (kc < 7) {
      na = *(const s16x8*)(ap + (kc + 1) * 32);
#pragma unroll
      for (int t = 0; t < 8; ++t) nb[t] = *(const s16x8*)(bp + t * 4096 + (kc + 1) * 32);
    }
    ABF a; a.s = ca;
#pragma unroll
    for (int t = 0; t < 8; ++t) {
      ABF b; b.s = cb[t];
      acc[t] = __builtin_amdgcn_mfma_f32_16x16x32_bf16(a.v, b.v, acc[t], 0, 0, 0);
    }
    if (kc < 7) {
      ca = na;
#pragma unroll
      for (int t = 0; t < 8; ++t) cb[t] = nb[t];
    }
  }
#pragma unroll
  for (int t = 0; t < 8; ++t) {
    int j = wid * 128 + t * 16 + lc;
    int sflag = j >> 8, h = (j >> 5) & 7, d = j & 31;
#pragma unroll
    for (int r = 0; r < 4; ++r) {
      int row = rowbase + lg * 4 + r;
      int b = row >> 10, m = row & 1023;
      unsigned short v = f2bf(acc[t][r]);
      if (sflag == 0) kmat[(size_t)((b * 8 + h) * 1024 + m) * 32 + d] = v;
      else            vt[(size_t)((b * 8 + h) * 32 + d) * 1024 + m] = v;
    }
  }
}

// ---------------- flash attention: LDS-staged K/V shared by 4 waves, double-buffered ----------------
// grid 1024 blocks (XCD-swizzled), 4 waves x 32 q-rows each. Max-free log2 softmax.
__global__ __launch_bounds__(256, 4) void k_attn(const unsigned short* __restrict__ q_s,
                                                 const unsigned short* __restrict__ kmat,
                                                 const unsigned short* __restrict__ vt,
                                                 const float* __restrict__ conf,
                                                 unsigned short* __restrict__ xat) {
  __shared__ __align__(16) unsigned short Kl[2][2048];  // [64 rows][32 d], chunk^(row&3) swizzle
  __shared__ __align__(16) unsigned short Vl[2][2048];  // [32 d][64 k],   chunk^(d&7)  swizzle
  __shared__ __align__(16) float Cf[2][64];
  __shared__ __align__(16) unsigned short p_lds[8192];  // [4 wid][2 g][16 q][64 k]

  int tid = threadIdx.x;
  int wid = tid >> 6, lane = tid & 63, lg = lane >> 4, lc = lane & 15;
  // XCD swizzle: 8 heads per XCD, all 16 q-tiles of a head on the same XCD
  int bid = blockIdx.x;
  int xcd = bid & 7, slot = bid >> 3;
  int bh = xcd * 8 + (slot >> 4);
  int qt = slot & 15;
  int b = bh >> 3, h = bh & 7;
  int qbase = qt * 128 + wid * 32;

  ABF qf[2];
  qf[0].s = *(const s16x8*)(q_s + (size_t)(bh * 2048 + qbase + lc) * 32 + lg * 8);
  qf[1].s = *(const s16x8*)(q_s + (size_t)(bh * 2048 + qbase + 16 + lc) * 32 + lg * 8);

  ABF ones;
#pragma unroll
  for (int i = 0; i < 8; ++i) ones.s[i] = (short)0x3F80;  // bf16 1.0

  f32x4 oacc[2][2] = {};
  f32x4 lacc[2] = {};

  // ---- staging addressing (per thread) ----
  int krow = tid >> 2, kch = tid & 3;
  const unsigned short* kgp = kmat + (size_t)bh * 32768 + krow * 32 + kch * 8;
  int kdst = krow * 32 + ((kch ^ (krow & 3)) * 8);
  int vd = tid >> 3, vch = tid & 7;
  const unsigned short* vgp = vt + (size_t)bh * 32768 + vd * 1024 + vch * 8;
  int vdst = vd * 64 + ((vch ^ (vd & 7)) * 8);
  const float* cgp = conf + b * 1024 + (tid & 15) * 4;

  // ---- compute-side LDS offsets (shorts/floats) ----
  int kf_off[4];
#pragma unroll
  for (int t = 0; t < 4; ++t) kf_off[t] = (t * 16 + lc) * 32 + ((lg ^ (lc & 3)) * 8);
  int vb_off[2][2];
#pragma unroll
  for (int c = 0; c < 2; ++c)
#pragma unroll
    for (int dh = 0; dh < 2; ++dh)
      vb_off[c][dh] = (dh * 16 + lc) * 64 + (((4 * c + lg) ^ (lc & 7)) * 8);
  int c4_off = lg * 4;

  // p_lds swizzled offsets: row = lc (128B), slot' = slot ^ (lc&7)
  unsigned short* ldsrow = p_lds + (wid * 2 * 16 + lc) * 64;
  int sw = lc & 7;
  int w_off[4], r_off[2];
#pragma unroll
  for (int t = 0; t < 4; ++t)
    w_off[t] = (((2 * t + (lg >> 1)) ^ sw) << 3) + ((lg & 1) << 2);
#pragma unroll
  for (int p = 0; p < 2; ++p)
    r_off[p] = ((p * 4 + lg) ^ sw) << 3;

  // ---- stage tile 0 ----
  s16x8 pk = *(const s16x8*)(kgp);
  s16x8 pv = *(const s16x8*)(vgp);
  f32x4 pc;
  if (tid < 16) pc = *(const f32x4*)(cgp);
  *(s16x8*)(&Kl[0][kdst]) = pk;
  *(s16x8*)(&Vl[0][vdst]) = pv;
  if (tid < 16) *(f32x4*)(&Cf[0][tid * 4]) = pc;
  __syncthreads();

#pragma unroll 2
  for (int it = 0; it < 16; ++it) {
    const int buf = it & 1;
    if (it < 15) {  // prefetch next tile into registers (latency hides under compute)
      pk = *(const s16x8*)(kgp + (it + 1) * 2048);
      pv = *(const s16x8*)(vgp + (it + 1) * 64);
      if (tid < 16) pc = *(const f32x4*)(cgp + (it + 1) * 64);
    }
    // ---- compute on buf ----
    ABF kf[4]; f32x4 c4[4];
#pragma unroll
    for (int t = 0; t < 4; ++t) {
      kf[t].s = *(const s16x8*)(&Kl[buf][kf_off[t]]);
      c4[t] = *(const f32x4*)(&Cf[buf][t * 16 + c4_off]);
    }
    ABF vb[2][2];
#pragma unroll
    for (int c = 0; c < 2; ++c)
#pragma unroll
      for (int dh = 0; dh < 2; ++dh)
        vb[c][dh].s = *(const s16x8*)(&Vl[buf][vb_off[c][dh]]);

    // swapped QK^T: lane holds q=lc, k rows
#pragma unroll
    for (int g = 0; g < 2; ++g) {
      unsigned short* lrow = ldsrow + g * 1024;
#pragma unroll
      for (int t = 0; t < 4; ++t) {
        f32x4 st = __builtin_amdgcn_mfma_f32_16x16x32_bf16(kf[t].v, qf[g].v, c4[t], 0, 0, 0);
        f32x4 pt;
        pt[0] = __builtin_amdgcn_exp2f(st[0]);
        pt[1] = __builtin_amdgcn_exp2f(st[1]);
        pt[2] = __builtin_amdgcn_exp2f(st[2]);
        pt[3] = __builtin_amdgcn_exp2f(st[3]);
        u32x2 w;
        w.x = cvt_pk_bf16(pt[0], pt[1]);
        w.y = cvt_pk_bf16(pt[2], pt[3]);
        *(u32x2*)(lrow + w_off[t]) = w;
      }
    }
    // PV + row-sum via ones-MFMA
#pragma unroll
    for (int g = 0; g < 2; ++g) {
      unsigned short* lrow = ldsrow + g * 1024;
      ABF pa0, pa1;
      pa0.s = *(const s16x8*)(lrow + r_off[0]);
      pa1.s = *(const s16x8*)(lrow + r_off[1]);
      oacc[g][0] = __builtin_amdgcn_mfma_f32_16x16x32_bf16(pa0.v, vb[0][0].v, oacc[g][0], 0, 0, 0);
      oacc[g][1] = __builtin_amdgcn_mfma_f32_16x16x32_bf16(pa0.v, vb[0][1].v, oacc[g][1], 0, 0, 0);
      lacc[g]    = __builtin_amdgcn_mfma_f32_16x16x32_bf16(pa0.v, ones.v,     lacc[g],    0, 0, 0);
      oacc[g][0] = __builtin_amdgcn_mfma_f32_16x16x32_bf16(pa1.v, vb[1][0].v, oacc[g][0], 0, 0, 0);
      oacc[g][1] = __builtin_amdgcn_mfma_f32_16x16x32_bf16(pa1.v, vb[1][1].v, oacc[g][1], 0, 0, 0);
      lacc[g]    = __builtin_amdgcn_mfma_f32_16x16x32_bf16(pa1.v, ones.v,     lacc[g],    0, 0, 0);
    }
    // ---- write prefetched tile to the other buffer ----
    if (it < 15) {
      *(s16x8*)(&Kl[buf ^ 1][kdst]) = pk;
      *(s16x8*)(&Vl[buf ^ 1][vdst]) = pv;
      if (tid < 16) *(f32x4*)(&Cf[buf ^ 1][tid * 4]) = pc;
    }
    __syncthreads();
  }

#pragma unroll
  for (int g = 0; g < 2; ++g) {
#pragma unroll
    for (int r = 0; r < 4; ++r) {
      float inv = 1.0f / lacc[g][r];
      int q = qbase + g * 16 + lg * 4 + r;
      xat[(size_t)(b * 2048 + q) * 256 + h * 32 + lc] = f2bf(oacc[g][0][r] * inv);
      xat[(size_t)(b * 2048 + q) * 256 + h * 32 + 16 + lc] = f2bf(oacc[g][1][r] * inv);
    }
  }
}

// ---------------- final projection (16384x256, K=256) + bias -> f32, 32 rows/block, prefetch ----------------

__global__ __launch_bounds__(256, 2) void k_proj(const unsigned short* __restrict__ xat,
                                                 const unsigned short* __restrict__ wb,
                                                 const float* __restrict__ pb,
                                                 float* __restrict__ out) {
  int tid = threadIdx.x;
  int wid = tid >> 6, lane = tid & 63, lg = lane >> 4, lc = lane & 15;
  int rowbase = blockIdx.x * 32;
  f32x4 acc[2][4] = {};
  const unsigned short* ap0 = xat + (size_t)(rowbase + lc) * 256 + lg * 8;
  const unsigned short* ap1 = ap0 + 16 * 256;
  const unsigned short* bp = wb + (size_t)(wid * 64 + lc) * 256 + lg * 8;
  s16x8 ca0 = *(const s16x8*)(ap0), ca1 = *(const s16x8*)(ap1);
  s16x8 cb[4];
#pragma unroll
  for (int t = 0; t < 4; ++t) cb[t] = *(const s16x8*)(bp + t * 4096);
#pragma unroll
  for (int kc = 0; kc < 8; ++kc) {
    s16x8 na0, na1, nb[4];
    if (kc < 7) {
      na0 = *(const s16x8*)(ap0 + (kc + 1) * 32);
      na1 = *(const s16x8*)(ap1 + (kc + 1) * 32);
#pragma unroll
      for (int t = 0; t < 4; ++t) nb[t] = *(const s16x8*)(bp + t * 4096 + (kc + 1) * 32);
    }
    ABF a0, a1; a0.s = ca0; a1.s = ca1;
#pragma unroll
    for (int t = 0; t < 4; ++t) {
      ABF b; b.s = cb[t];
      acc[0][t] = __builtin_amdgcn_mfma_f32_16x16x32_bf16(a0.v, b.v, acc[0][t], 0, 0, 0);
      acc[1][t] = __builtin_amdgcn_mfma_f32_16x16x32_bf16(a1.v, b.v, acc[1][t], 0, 0, 0);
    }
    if (kc < 7) {
      ca0 = na0; ca1 = na1;
#pragma unroll
      for (int t = 0; t < 4; ++t) cb[t] = nb[t];
    }
  }
#pragma unroll
  for (int s = 0; s < 2; ++s)
#pragma unroll
    for (int t = 0; t < 4; ++t) {
      int col = wid * 64 + t * 16 + lc;
      float bias = pb[col];
#pragma unroll
      for (int r = 0; r < 4; ++r) {
        int row = rowbase + s * 16 + lg * 4 + r;
        out[(size_t)row * 256 + col] = acc[s][t][r] + bias;
      }
    }
}

// ---------------- launch ----------------

extern "C" void kernel_launch(void* const* d_in, const int* in_sizes, int n_in,
                              void* d_out, int out_size, void* d_ws, size_t ws_size,
                              hipStream_t stream) {
  (void)in_sizes; (void)n_in; (void)out_size; (void)ws_size;
  const float* q_x         = (const float*)d_in[0];
  const float* kv_x        = (const float*)d_in[1];
  const float* token_score = (const float*)d_in[2];
  const int*   idx_token   = (const int*)d_in[3];
  const float* q_w         = (const float*)d_in[4];
  const float* kv_w        = (const float*)d_in[5];
  const float* proj_w      = (const float*)d_in[6];
  const float* proj_b      = (const float*)d_in[7];
  const float* sr_w        = (const float*)d_in[8];
  const float* sr_b        = (const float*)d_in[9];
  const float* ln_w        = (const float*)d_in[10];
  const float* ln_b        = (const float*)d_in[11];
  float* out = (float*)d_out;

  char* ws = (char*)d_ws;
  unsigned short* q_s   = (unsigned short*)(ws + 0);          // 64*2048*32  bf16 = 8 MB
  unsigned short* x4    = (unsigned short*)(ws + 8388608);    // 8192*1024   bf16 = 16 MB
  unsigned short* xat   = (unsigned short*)(ws + 8388608);    // aliases x4 (dead by attn time)
  unsigned short* w4t   = (unsigned short*)(ws + 25165824);   // 256*1024    bf16
  unsigned short* kv_ln = (unsigned short*)(ws + 25690112);   // 8192*256    bf16
  unsigned short* kmat  = (unsigned short*)(ws + 29884416);   // 64*1024*32  bf16
  unsigned short* vt    = (unsigned short*)(ws + 34078720);   // 64*32*1024  bf16
  float*          confp = (float*)(ws + 38273024);            // 8*1024      f32
  unsigned short* q_wb  = (unsigned short*)(ws + 46694400);   // 256*256     bf16
  unsigned short* kv_wb = (unsigned short*)(ws + 46825472);   // 512*256     bf16
  unsigned short* p_wb  = (unsigned short*)(ws + 47087616);   // 256*256     bf16

  k_pre<<<dim3(10272), dim3(256), 0, stream>>>(q_w, kv_w, proj_w, sr_w, token_score, idx_token,
                                               kv_x, q_wb, kv_wb, p_wb, w4t, confp, x4);
  k_qc<<<dim3(1024), dim3(256), 0, stream>>>(q_x, q_wb, q_s, x4, w4t, sr_b, ln_w, ln_b, kv_ln);
  k_kvproj<<<dim3(512), dim3(256), 0, stream>>>(kv_ln, kv_wb, kmat, vt);
  k_attn<<<dim3(1024), dim3(256), 0, stream>>>(q_s, kmat, vt, confp, xat);
  k_proj<<<dim3(512), dim3(256), 0, stream>>>(xat, p_wb, proj_b, out);
}

// Round 6
// 80.763 us; speedup vs baseline: 1.6679x; 1.6679x over previous
//
#include <hip/hip_runtime.h>

#define LOG2E 1.4426950408889634f

typedef float f32x4 __attribute__((ext_vector_type(4)));
typedef short s16x8 __attribute__((ext_vector_type(8)));
typedef __bf16 bf16x8 __attribute__((ext_vector_type(8)));
typedef unsigned int u32x2 __attribute__((ext_vector_type(2)));

union ABF { s16x8 s; bf16x8 v; };
union PKU { unsigned int u[4]; s16x8 s; bf16x8 v; };

__device__ __forceinline__ unsigned short f2bf(float f) {
  unsigned int u = __builtin_bit_cast(unsigned int, f);
  u += 0x7fffu + ((u >> 16) & 1u);
  return (unsigned short)(u >> 16);
}

__device__ __forceinline__ unsigned int cvt_pk_bf16(float a, float b) {
  unsigned int r;
  asm("v_cvt_pk_bf16_f32 %0, %1, %2" : "=v"(r) : "v"(a), "v"(b));
  return r;  // low16 = bf16(a), high16 = bf16(b)
}

// ---------------- k_pre: all converts + conv-weight repack + conf + gather ----------------

__global__ __launch_bounds__(256) void k_pre(const float* __restrict__ q_w,
                                             const float* __restrict__ kv_w,
                                             const float* __restrict__ proj_w,
                                             const float* __restrict__ sr_w,
                                             const float* __restrict__ token_score,
                                             const int* __restrict__ idx_token,
                                             const float* __restrict__ kv_x,
                                             unsigned short* __restrict__ q_wb,
                                             unsigned short* __restrict__ kv_wb,
                                             unsigned short* __restrict__ p_wb,
                                             unsigned short* __restrict__ w4t,
                                             float* __restrict__ conf,
                                             unsigned short* __restrict__ x4) {
  int bid = blockIdx.x, t = threadIdx.x;
  if (bid < 256) { int i = bid * 256 + t; q_wb[i] = f2bf(q_w[i]); return; }
  if (bid < 768) { int i = (bid - 256) * 256 + t; kv_wb[i] = f2bf(kv_w[i]); return; }
  if (bid < 1024) { int i = (bid - 768) * 256 + t; p_wb[i] = f2bf(proj_w[i]); return; }
  if (bid < 2048) {
    // w4t[co][k], k = (dh*2+dw)*256 + ci ; from sr_w[co][ci][dh][dw]
    int idx = (bid - 1024) * 256 + t;
    int co = idx >> 10, k = idx & 1023;
    int slot = k >> 8, ci = k & 255;
    int dh = slot >> 1, dw = slot & 1;
    w4t[idx] = f2bf(sr_w[((co * 256 + ci) * 2 + dh) * 2 + dw]);
    return;
  }
  if (bid < 2080) {
    // conf[b][m] = log2e * mean_{2x2}(token_score gathered) / 1.000001
    int i = (bid - 2048) * 256 + t;  // B*1024 = 8192
    int b = i >> 10, m = i & 1023;
    int h = m >> 5, w = m & 31;
    float s = 0.f;
#pragma unroll
    for (int dh = 0; dh < 2; ++dh)
#pragma unroll
      for (int dw = 0; dw < 2; ++dw) {
        int j = (2 * h + dh) * 64 + (2 * w + dw);
        s += token_score[b * 2048 + idx_token[b * 4096 + j]];
      }
    conf[i] = s * 0.25f * (1.0f / 1.000001f) * LOG2E;
    return;
  }
  // gather: x4 rearranged for conv-as-GEMM; 4 tokens/block, f32x4 vectorized
  int gi = (bid - 2080) * 4 + (t >> 6);  // 0..32767
  int c4i = t & 63;
  int b = gi >> 12, i = gi & 4095;
  int tok = idx_token[gi];
  int y = i >> 6, x = i & 63;
  int row = ((y >> 1) << 5) + (x >> 1);
  int slot = ((y & 1) << 1) + (x & 1);
  const float inv1 = 1.0f / 1.000001f;
  f32x4 v = *(const f32x4*)(kv_x + (size_t)(b * 2048 + tok) * 256 + c4i * 4);
  u32x2 w;
  w.x = cvt_pk_bf16(v[0] * inv1, v[1] * inv1);
  w.y = cvt_pk_bf16(v[2] * inv1, v[3] * inv1);
  *(u32x2*)(x4 + (size_t)((b * 1024 + row) * 4 + slot) * 256 + c4i * 4) = w;
}

// ---------------- unified 32x256 LDS-staged GEMM tile ----------------
// OP: 0=conv(+bias+LN->kv_ln), 1=qproj(->q_s scaled), 2=kvproj(->kmat/vt), 3=proj(+bias->f32)
// Tile: 32 rows x 256 cols, BK=64, 4 waves (wave = 64-col strip x 32 rows).
// A,B double-buffered in LDS with chunk^(row&7) swizzle; reg-staged global->LDS.

template<int OP>
__device__ __forceinline__ void gemm_tile(int rowbase, int ntbase,
                                          const void* __restrict__ Ap,
                                          const unsigned short* __restrict__ Bp,
                                          const float* __restrict__ bias,
                                          const float* __restrict__ lnw,
                                          const float* __restrict__ lnb,
                                          unsigned short* __restrict__ o16,
                                          float* __restrict__ of32,
                                          unsigned short* __restrict__ o16b,
                                          unsigned char* __restrict__ lds) {
  constexpr int KSTEPS = (OP == 0) ? 16 : 4;
  constexpr bool AF32 = (OP == 1);
  constexpr int LD = (OP == 0) ? 1024 : 256;

  unsigned short* As0 = (unsigned short*)lds;          // 32x64 bf16 = 4 KB
  unsigned short* As1 = As0 + 2048;
  unsigned short* Bs0 = As0 + 4096;                    // 256x64 bf16 = 32 KB
  unsigned short* Bs1 = Bs0 + 16384;

  int tid = threadIdx.x;
  int wid = tid >> 6, lane = tid & 63, lg = lane >> 4, lc = lane & 15;

  // staging addressing
  int arow = tid >> 3, ac = tid & 7;                   // A: 1 chunk/thread
  int adst = arow * 64 + ((ac ^ (arow & 7)) * 8);
  const unsigned short* Aus = nullptr; const float* Afs = nullptr;
  if (AF32) Afs = (const float*)Ap + (size_t)(rowbase + arow) * LD + ac * 8;
  else      Aus = (const unsigned short*)Ap + (size_t)(rowbase + arow) * LD + ac * 8;
  int brg = tid >> 3, bc = tid & 7;                    // B: 8 rows/thread (stride 32)
  const unsigned short* Bsrc = Bp + (size_t)(ntbase + brg) * LD + bc * 8;
  int bdst = brg * 64 + ((bc ^ (brg & 7)) * 8);

  s16x8 ra; f32x4 ra0, ra1; s16x8 rb[8];
  f32x4 acc[2][4] = {};

  // prologue: stage step 0
  {
    if (AF32) { ra0 = *(const f32x4*)(Afs); ra1 = *(const f32x4*)(Afs + 4); }
    else      { ra = *(const s16x8*)(Aus); }
#pragma unroll
    for (int i = 0; i < 8; ++i) rb[i] = *(const s16x8*)(Bsrc + (size_t)i * 32 * LD);
    if (AF32) {
      PKU aw;
      aw.u[0] = cvt_pk_bf16(ra0[0], ra0[1]);
      aw.u[1] = cvt_pk_bf16(ra0[2], ra0[3]);
      aw.u[2] = cvt_pk_bf16(ra1[0], ra1[1]);
      aw.u[3] = cvt_pk_bf16(ra1[2], ra1[3]);
      *(s16x8*)(As0 + adst) = aw.s;
    } else {
      *(s16x8*)(As0 + adst) = ra;
    }
#pragma unroll
    for (int i = 0; i < 8; ++i) *(s16x8*)(Bs0 + bdst + i * 2048) = rb[i];
  }
  __syncthreads();

#pragma unroll 2
  for (int it = 0; it < KSTEPS - 1; ++it) {
    const unsigned short* Ac = (it & 1) ? As1 : As0;
    const unsigned short* Bc = (it & 1) ? Bs1 : Bs0;
    unsigned short* An = (it & 1) ? As0 : As1;
    unsigned short* Bn = (it & 1) ? Bs0 : Bs1;
    int ko = (it + 1) * 64;
    // issue next-step loads
    if (AF32) { ra0 = *(const f32x4*)(Afs + ko); ra1 = *(const f32x4*)(Afs + ko + 4); }
    else      { ra = *(const s16x8*)(Aus + ko); }
#pragma unroll
    for (int i = 0; i < 8; ++i) rb[i] = *(const s16x8*)(Bsrc + (size_t)i * 32 * LD + ko);
    // compute on current buffer
#pragma unroll
    for (int kc = 0; kc < 2; ++kc) {
      int swz = ((kc * 4 + lg) ^ (lc & 7)) * 8;
      ABF a0, a1;
      a0.s = *(const s16x8*)(Ac + lc * 64 + swz);
      a1.s = *(const s16x8*)(Ac + (16 + lc) * 64 + swz);
#pragma unroll
      for (int cf = 0; cf < 4; ++cf) {
        ABF bf; bf.s = *(const s16x8*)(Bc + (wid * 64 + cf * 16 + lc) * 64 + swz);
        acc[0][cf] = __builtin_amdgcn_mfma_f32_16x16x32_bf16(a0.v, bf.v, acc[0][cf], 0, 0, 0);
        acc[1][cf] = __builtin_amdgcn_mfma_f32_16x16x32_bf16(a1.v, bf.v, acc[1][cf], 0, 0, 0);
      }
    }
    // write staged regs to the other buffer
    if (AF32) {
      PKU aw;
      aw.u[0] = cvt_pk_bf16(ra0[0], ra0[1]);
      aw.u[1] = cvt_pk_bf16(ra0[2], ra0[3]);
      aw.u[2] = cvt_pk_bf16(ra1[0], ra1[1]);
      aw.u[3] = cvt_pk_bf16(ra1[2], ra1[3]);
      *(s16x8*)(An + adst) = aw.s;
    } else {
      *(s16x8*)(An + adst) = ra;
    }
#pragma unroll
    for (int i = 0; i < 8; ++i) *(s16x8*)(Bn + bdst + i * 2048) = rb[i];
    __syncthreads();
  }
  // last step compute
  {
    const unsigned short* Ac = ((KSTEPS - 1) & 1) ? As1 : As0;
    const unsigned short* Bc = ((KSTEPS - 1) & 1) ? Bs1 : Bs0;
#pragma unroll
    for (int kc = 0; kc < 2; ++kc) {
      int swz = ((kc * 4 + lg) ^ (lc & 7)) * 8;
      ABF a0, a1;
      a0.s = *(const s16x8*)(Ac + lc * 64 + swz);
      a1.s = *(const s16x8*)(Ac + (16 + lc) * 64 + swz);
#pragma unroll
      for (int cf = 0; cf < 4; ++cf) {
        ABF bf; bf.s = *(const s16x8*)(Bc + (wid * 64 + cf * 16 + lc) * 64 + swz);
        acc[0][cf] = __builtin_amdgcn_mfma_f32_16x16x32_bf16(a0.v, bf.v, acc[0][cf], 0, 0, 0);
        acc[1][cf] = __builtin_amdgcn_mfma_f32_16x16x32_bf16(a1.v, bf.v, acc[1][cf], 0, 0, 0);
      }
    }
  }
  __syncthreads();

  // ---- epilogues ----
  if constexpr (OP == 1) {
    const float qs = 0.17677669529663687f * LOG2E;
#pragma unroll
    for (int rf = 0; rf < 2; ++rf)
#pragma unroll
      for (int cf = 0; cf < 4; ++cf) {
        int col = wid * 64 + cf * 16 + lc;
        int h = col >> 5, d = col & 31;
#pragma unroll
        for (int r = 0; r < 4; ++r) {
          int row = rowbase + rf * 16 + lg * 4 + r;
          int b = row >> 11, n = row & 2047;
          o16[(size_t)((b * 8 + h) * 2048 + n) * 32 + d] = f2bf(acc[rf][cf][r] * qs);
        }
      }
  } else if constexpr (OP == 2) {
#pragma unroll
    for (int rf = 0; rf < 2; ++rf)
#pragma unroll
      for (int cf = 0; cf < 4; ++cf) {
        int j = ntbase + wid * 64 + cf * 16 + lc;
        int sflag = j >> 8, h = (j >> 5) & 7, d = j & 31;
#pragma unroll
        for (int r = 0; r < 4; ++r) {
          int row = rowbase + rf * 16 + lg * 4 + r;
          int b = row >> 10, m = row & 1023;
          unsigned short v = f2bf(acc[rf][cf][r]);
          if (sflag == 0) o16[(size_t)((b * 8 + h) * 1024 + m) * 32 + d] = v;
          else            o16b[(size_t)((b * 8 + h) * 32 + d) * 1024 + m] = v;
        }
      }
  } else if constexpr (OP == 3) {
#pragma unroll
    for (int rf = 0; rf < 2; ++rf)
#pragma unroll
      for (int cf = 0; cf < 4; ++cf) {
        int col = wid * 64 + cf * 16 + lc;
        float bv = bias[col];
#pragma unroll
        for (int r = 0; r < 4; ++r) {
          int row = rowbase + rf * 16 + lg * 4 + r;
          of32[(size_t)row * 256 + col] = acc[rf][cf][r] + bv;
        }
      }
  } else {
    // conv: bias + LayerNorm over 256 cols, write kv_ln bf16. srow aliases staging LDS.
    float* srow = (float*)lds;  // [32][260]
#pragma unroll
    for (int rf = 0; rf < 2; ++rf)
#pragma unroll
      for (int cf = 0; cf < 4; ++cf) {
        int col = wid * 64 + cf * 16 + lc;
        float bv = bias[col];
#pragma unroll
        for (int r = 0; r < 4; ++r)
          srow[(rf * 16 + lg * 4 + r) * 260 + col] = acc[rf][cf][r] + bv;
      }
    __syncthreads();
#pragma unroll
    for (int s = 0; s < 2; ++s) {
      int r = s * 16 + (tid >> 4), c16 = tid & 15;
      float vals[16];
      float sm = 0.f, ss = 0.f;
#pragma unroll
      for (int i = 0; i < 16; ++i) {
        float v = srow[r * 260 + c16 * 16 + i];
        vals[i] = v; sm += v; ss += v * v;
      }
#pragma unroll
      for (int m = 1; m < 16; m <<= 1) {
        sm += __shfl_xor(sm, m, 64);
        ss += __shfl_xor(ss, m, 64);
      }
      float mu = sm * (1.0f / 256.0f);
      float var = ss * (1.0f / 256.0f) - mu * mu;
      float rstd = rsqrtf(var + 1e-5f);
      s16x8 w0, w1;
#pragma unroll
      for (int i = 0; i < 8; ++i) {
        int c = c16 * 16 + i;
        w0[i] = (short)f2bf((vals[i] - mu) * rstd * lnw[c] + lnb[c]);
      }
#pragma unroll
      for (int i = 0; i < 8; ++i) {
        int c = c16 * 16 + 8 + i;
        w1[i] = (short)f2bf((vals[8 + i] - mu) * rstd * lnw[c] + lnb[c]);
      }
      *(s16x8*)(o16 + (size_t)(rowbase + r) * 256 + c16 * 16) = w0;
      *(s16x8*)(o16 + (size_t)(rowbase + r) * 256 + c16 * 16 + 8) = w1;
    }
  }
}

// ---------------- GEMM kernel wrappers ----------------

__global__ __launch_bounds__(256, 2) void k_qc(const float* __restrict__ q_x,
                                               const unsigned short* __restrict__ q_wb,
                                               unsigned short* __restrict__ q_s,
                                               const unsigned short* __restrict__ x4,
                                               const unsigned short* __restrict__ w4t,
                                               const float* __restrict__ sr_b,
                                               const float* __restrict__ ln_w,
                                               const float* __restrict__ ln_b,
                                               unsigned short* __restrict__ kv_ln) {
  __shared__ __align__(16) unsigned char lds[73728];
  int bid = blockIdx.x;
  if (bid < 256)
    gemm_tile<0>(bid * 32, 0, x4, w4t, sr_b, ln_w, ln_b, kv_ln, nullptr, nullptr, lds);
  else
    gemm_tile<1>((bid - 256) * 32, 0, q_x, q_wb, nullptr, nullptr, nullptr, q_s, nullptr, nullptr, lds);
}

__global__ __launch_bounds__(256, 2) void k_kvproj(const unsigned short* __restrict__ kv_ln,
                                                   const unsigned short* __restrict__ kv_wb,
                                                   unsigned short* __restrict__ kmat,
                                                   unsigned short* __restrict__ vt) {
  __shared__ __align__(16) unsigned char lds[73728];
  int bid = blockIdx.x;
  gemm_tile<2>((bid & 255) * 32, (bid >> 8) * 256, kv_ln, kv_wb, nullptr, nullptr, nullptr,
               kmat, nullptr, vt, lds);
}

__global__ __launch_bounds__(256, 2) void k_proj(const unsigned short* __restrict__ xat,
                                                 const unsigned short* __restrict__ p_wb,
                                                 const float* __restrict__ pb,
                                                 float* __restrict__ out) {
  __shared__ __align__(16) unsigned char lds[73728];
  gemm_tile<3>(blockIdx.x * 32, 0, xat, p_wb, pb, nullptr, nullptr, nullptr, out, nullptr, lds);
}

// ---------------- flash attention: LDS-staged K/V shared by 4 waves, double-buffered ----------------
// grid 1024 blocks (XCD-swizzled), 4 waves x 32 q-rows each. Max-free log2 softmax.
__global__ __launch_bounds__(256, 4) void k_attn(const unsigned short* __restrict__ q_s,
                                                 const unsigned short* __restrict__ kmat,
                                                 const unsigned short* __restrict__ vt,
                                                 const float* __restrict__ conf,
                                                 unsigned short* __restrict__ xat) {
  __shared__ __align__(16) unsigned short Kl[2][2048];  // [64 rows][32 d], chunk^(row&3) swizzle
  __shared__ __align__(16) unsigned short Vl[2][2048];  // [32 d][64 k],   chunk^(d&7)  swizzle
  __shared__ __align__(16) float Cf[2][64];
  __shared__ __align__(16) unsigned short p_lds[8192];  // [4 wid][2 g][16 q][64 k]

  int tid = threadIdx.x;
  int wid = tid >> 6, lane = tid & 63, lg = lane >> 4, lc = lane & 15;
  // XCD swizzle: 8 heads per XCD, all 16 q-tiles of a head on the same XCD
  int bid = blockIdx.x;
  int xcd = bid & 7, slot = bid >> 3;
  int bh = xcd * 8 + (slot >> 4);
  int qt = slot & 15;
  int b = bh >> 3, h = bh & 7;
  int qbase = qt * 128 + wid * 32;

  ABF qf[2];
  qf[0].s = *(const s16x8*)(q_s + (size_t)(bh * 2048 + qbase + lc) * 32 + lg * 8);
  qf[1].s = *(const s16x8*)(q_s + (size_t)(bh * 2048 + qbase + 16 + lc) * 32 + lg * 8);

  ABF ones;
#pragma unroll
  for (int i = 0; i < 8; ++i) ones.s[i] = (short)0x3F80;  // bf16 1.0

  f32x4 oacc[2][2] = {};
  f32x4 lacc[2] = {};

  // ---- staging addressing (per thread) ----
  int krow = tid >> 2, kch = tid & 3;
  const unsigned short* kgp = kmat + (size_t)bh * 32768 + krow * 32 + kch * 8;
  int kdst = krow * 32 + ((kch ^ (krow & 3)) * 8);
  int vd = tid >> 3, vch = tid & 7;
  const unsigned short* vgp = vt + (size_t)bh * 32768 + vd * 1024 + vch * 8;
  int vdst = vd * 64 + ((vch ^ (vd & 7)) * 8);
  const float* cgp = conf + b * 1024 + (tid & 15) * 4;

  // ---- compute-side LDS offsets (shorts/floats) ----
  int kf_off[4];
#pragma unroll
  for (int t = 0; t < 4; ++t) kf_off[t] = (t * 16 + lc) * 32 + ((lg ^ (lc & 3)) * 8);
  int vb_off[2][2];
#pragma unroll
  for (int c = 0; c < 2; ++c)
#pragma unroll
    for (int dh = 0; dh < 2; ++dh)
      vb_off[c][dh] = (dh * 16 + lc) * 64 + (((4 * c + lg) ^ (lc & 7)) * 8);
  int c4_off = lg * 4;

  // p_lds swizzled offsets: row = lc (128B), slot' = slot ^ (lc&7)
  unsigned short* ldsrow = p_lds + (wid * 2 * 16 + lc) * 64;
  int sw = lc & 7;
  int w_off[4], r_off[2];
#pragma unroll
  for (int t = 0; t < 4; ++t)
    w_off[t] = (((2 * t + (lg >> 1)) ^ sw) << 3) + ((lg & 1) << 2);
#pragma unroll
  for (int p = 0; p < 2; ++p)
    r_off[p] = ((p * 4 + lg) ^ sw) << 3;

  // ---- stage tile 0 ----
  s16x8 pk = *(const s16x8*)(kgp);
  s16x8 pv = *(const s16x8*)(vgp);
  f32x4 pc;
  if (tid < 16) pc = *(const f32x4*)(cgp);
  *(s16x8*)(&Kl[0][kdst]) = pk;
  *(s16x8*)(&Vl[0][vdst]) = pv;
  if (tid < 16) *(f32x4*)(&Cf[0][tid * 4]) = pc;
  __syncthreads();

#pragma unroll 2
  for (int it = 0; it < 16; ++it) {
    const int buf = it & 1;
    if (it < 15) {  // prefetch next tile into registers (latency hides under compute)
      pk = *(const s16x8*)(kgp + (it + 1) * 2048);
      pv = *(const s16x8*)(vgp + (it + 1) * 64);
      if (tid < 16) pc = *(const f32x4*)(cgp + (it + 1) * 64);
    }
    // ---- compute on buf ----
    ABF kf[4]; f32x4 c4[4];
#pragma unroll
    for (int t = 0; t < 4; ++t) {
      kf[t].s = *(const s16x8*)(&Kl[buf][kf_off[t]]);
      c4[t] = *(const f32x4*)(&Cf[buf][t * 16 + c4_off]);
    }
    ABF vb[2][2];
#pragma unroll
    for (int c = 0; c < 2; ++c)
#pragma unroll
      for (int dh = 0; dh < 2; ++dh)
        vb[c][dh].s = *(const s16x8*)(&Vl[buf][vb_off[c][dh]]);

    // swapped QK^T: lane holds q=lc, k rows
#pragma unroll
    for (int g = 0; g < 2; ++g) {
      unsigned short* lrow = ldsrow + g * 1024;
#pragma unroll
      for (int t = 0; t < 4; ++t) {
        f32x4 st = __builtin_amdgcn_mfma_f32_16x16x32_bf16(kf[t].v, qf[g].v, c4[t], 0, 0, 0);
        f32x4 pt;
        pt[0] = __builtin_amdgcn_exp2f(st[0]);
        pt[1] = __builtin_amdgcn_exp2f(st[1]);
        pt[2] = __builtin_amdgcn_exp2f(st[2]);
        pt[3] = __builtin_amdgcn_exp2f(st[3]);
        u32x2 w;
        w.x = cvt_pk_bf16(pt[0], pt[1]);
        w.y = cvt_pk_bf16(pt[2], pt[3]);
        *(u32x2*)(lrow + w_off[t]) = w;
      }
    }
    // PV + row-sum via ones-MFMA
#pragma unroll
    for (int g = 0; g < 2; ++g) {
      unsigned short* lrow = ldsrow + g * 1024;
      ABF pa0, pa1;
      pa0.s = *(const s16x8*)(lrow + r_off[0]);
      pa1.s = *(const s16x8*)(lrow + r_off[1]);
      oacc[g][0] = __builtin_amdgcn_mfma_f32_16x16x32_bf16(pa0.v, vb[0][0].v, oacc[g][0], 0, 0, 0);
      oacc[g][1] = __builtin_amdgcn_mfma_f32_16x16x32_bf16(pa0.v, vb[0][1].v, oacc[g][1], 0, 0, 0);
      lacc[g]    = __builtin_amdgcn_mfma_f32_16x16x32_bf16(pa0.v, ones.v,     lacc[g],    0, 0, 0);
      oacc[g][0] = __builtin_amdgcn_mfma_f32_16x16x32_bf16(pa1.v, vb[1][0].v, oacc[g][0], 0, 0, 0);
      oacc[g][1] = __builtin_amdgcn_mfma_f32_16x16x32_bf16(pa1.v, vb[1][1].v, oacc[g][1], 0, 0, 0);
      lacc[g]    = __builtin_amdgcn_mfma_f32_16x16x32_bf16(pa1.v, ones.v,     lacc[g],    0, 0, 0);
    }
    // ---- write prefetched tile to the other buffer ----
    if (it < 15) {
      *(s16x8*)(&Kl[buf ^ 1][kdst]) = pk;
      *(s16x8*)(&Vl[buf ^ 1][vdst]) = pv;
      if (tid < 16) *(f32x4*)(&Cf[buf ^ 1][tid * 4]) = pc;
    }
    __syncthreads();
  }

#pragma unroll
  for (int g = 0; g < 2; ++g) {
#pragma unroll
    for (int r = 0; r < 4; ++r) {
      float inv = 1.0f / lacc[g][r];
      int q = qbase + g * 16 + lg * 4 + r;
      xat[(size_t)(b * 2048 + q) * 256 + h * 32 + lc] = f2bf(oacc[g][0][r] * inv);
      xat[(size_t)(b * 2048 + q) * 256 + h * 32 + 16 + lc] = f2bf(oacc[g][1][r] * inv);
    }
  }
}

// ---------------- launch ----------------

extern "C" void kernel_launch(void* const* d_in, const int* in_sizes, int n_in,
                              void* d_out, int out_size, void* d_ws, size_t ws_size,
                              hipStream_t stream) {
  (void)in_sizes; (void)n_in; (void)out_size; (void)ws_size;
  const float* q_x         = (const float*)d_in[0];
  const float* kv_x        = (const float*)d_in[1];
  const float* token_score = (const float*)d_in[2];
  const int*   idx_token   = (const int*)d_in[3];
  const float* q_w         = (const float*)d_in[4];
  const float* kv_w        = (const float*)d_in[5];
  const float* proj_w      = (const float*)d_in[6];
  const float* proj_b      = (const float*)d_in[7];
  const float* sr_w        = (const float*)d_in[8];
  const float* sr_b        = (const float*)d_in[9];
  const float* ln_w        = (const float*)d_in[10];
  const float* ln_b        = (const float*)d_in[11];
  float* out = (float*)d_out;

  char* ws = (char*)d_ws;
  unsigned short* q_s   = (unsigned short*)(ws + 0);          // 64*2048*32  bf16 = 8 MB
  unsigned short* x4    = (unsigned short*)(ws + 8388608);    // 8192*1024   bf16 = 16 MB
  unsigned short* xat   = (unsigned short*)(ws + 8388608);    // aliases x4 (dead by attn time)
  unsigned short* w4t   = (unsigned short*)(ws + 25165824);   // 256*1024    bf16
  unsigned short* kv_ln = (unsigned short*)(ws + 25690112);   // 8192*256    bf16
  unsigned short* kmat  = (unsigned short*)(ws + 29884416);   // 64*1024*32  bf16
  unsigned short* vt    = (unsigned short*)(ws + 34078720);   // 64*32*1024  bf16
  float*          confp = (float*)(ws + 38273024);            // 8*1024      f32
  unsigned short* q_wb  = (unsigned short*)(ws + 46694400);   // 256*256     bf16
  unsigned short* kv_wb = (unsigned short*)(ws + 46825472);   // 512*256     bf16
  unsigned short* p_wb  = (unsigned short*)(ws + 47087616);   // 256*256     bf16

  k_pre<<<dim3(10272), dim3(256), 0, stream>>>(q_w, kv_w, proj_w, sr_w, token_score, idx_token,
                                               kv_x, q_wb, kv_wb, p_wb, w4t, confp, x4);
  k_qc<<<dim3(768), dim3(256), 0, stream>>>(q_x, q_wb, q_s, x4, w4t, sr_b, ln_w, ln_b, kv_ln);
  k_kvproj<<<dim3(512), dim3(256), 0, stream>>>(kv_ln, kv_wb, kmat, vt);
  k_attn<<<dim3(1024), dim3(256), 0, stream>>>(q_s, kmat, vt, confp, xat);
  k_proj<<<dim3(512), dim3(256), 0, stream>>>(xat, p_wb, proj_b, out);
}

// Round 9
// 79.689 us; speedup vs baseline: 1.6903x; 1.0135x over previous
//
#include <hip/hip_runtime.h>

#define LOG2E 1.4426950408889634f

typedef float f32x4 __attribute__((ext_vector_type(4)));
typedef short s16x8 __attribute__((ext_vector_type(8)));
typedef __bf16 bf16x8 __attribute__((ext_vector_type(8)));
typedef unsigned int u32x2 __attribute__((ext_vector_type(2)));

union ABF { s16x8 s; bf16x8 v; };
union PKU { unsigned int u[4]; s16x8 s; bf16x8 v; };

__device__ __forceinline__ unsigned short f2bf(float f) {
  unsigned int u = __builtin_bit_cast(unsigned int, f);
  u += 0x7fffu + ((u >> 16) & 1u);
  return (unsigned short)(u >> 16);
}

__device__ __forceinline__ unsigned int cvt_pk_bf16(float a, float b) {
  unsigned int r;
  asm("v_cvt_pk_bf16_f32 %0, %1, %2" : "=v"(r) : "v"(a), "v"(b));
  return r;  // low16 = bf16(a), high16 = bf16(b)
}

// ---------------- k_pre: weight converts + conv-weight repack + conf (gather now fused into conv) ----------------

__global__ __launch_bounds__(256) void k_pre(const float* __restrict__ q_w,
                                             const float* __restrict__ kv_w,
                                             const float* __restrict__ proj_w,
                                             const float* __restrict__ sr_w,
                                             const float* __restrict__ token_score,
                                             const int* __restrict__ idx_token,
                                             unsigned short* __restrict__ q_wb,
                                             unsigned short* __restrict__ kv_wb,
                                             unsigned short* __restrict__ p_wb,
                                             unsigned short* __restrict__ w4t,
                                             float* __restrict__ conf) {
  int bid = blockIdx.x, t = threadIdx.x;
  if (bid < 256) { int i = bid * 256 + t; q_wb[i] = f2bf(q_w[i]); return; }
  if (bid < 768) { int i = (bid - 256) * 256 + t; kv_wb[i] = f2bf(kv_w[i]); return; }
  if (bid < 1024) { int i = (bid - 768) * 256 + t; p_wb[i] = f2bf(proj_w[i]); return; }
  if (bid < 2048) {
    // w4t[co][k], k = (dh*2+dw)*256 + ci ; from sr_w[co][ci][dh][dw]
    int idx = (bid - 1024) * 256 + t;
    int co = idx >> 10, k = idx & 1023;
    int slot = k >> 8, ci = k & 255;
    int dh = slot >> 1, dw = slot & 1;
    w4t[idx] = f2bf(sr_w[((co * 256 + ci) * 2 + dh) * 2 + dw]);
    return;
  }
  // conf[b][m] = log2e * mean_{2x2}(token_score gathered) / 1.000001
  int i = (bid - 2048) * 256 + t;  // B*1024 = 8192
  int b = i >> 10, m = i & 1023;
  int h = m >> 5, w = m & 31;
  float s = 0.f;
#pragma unroll
  for (int dh = 0; dh < 2; ++dh)
#pragma unroll
    for (int dw = 0; dw < 2; ++dw) {
      int j = (2 * h + dh) * 64 + (2 * w + dw);
      s += token_score[b * 2048 + idx_token[b * 4096 + j]];
    }
  conf[i] = s * 0.25f * (1.0f / 1.000001f) * LOG2E;
}

// ---------------- unified 32x256 LDS-staged GEMM tile ----------------
// OP: 0=conv(+bias+LN->kv_ln, A gathered from kv_x f32), 1=qproj(A=q_x f32),
//     2=kvproj(->kmat/vt), 3=proj(+bias->f32)
// Tile: 32 rows x 256 cols, BK=64, 4 waves. A,B double-buffered in LDS,
// chunk^(row&7) swizzle; reg-staged global->LDS (issue-early, cvt+write-late).

template<int OP>
__device__ __forceinline__ void gemm_tile(int rowbase, int ntbase,
                                          const void* __restrict__ Ap,
                                          const unsigned short* __restrict__ Bp,
                                          const int* __restrict__ idxt,
                                          const float* __restrict__ bias,
                                          const float* __restrict__ lnw,
                                          const float* __restrict__ lnb,
                                          unsigned short* __restrict__ o16,
                                          float* __restrict__ of32,
                                          unsigned short* __restrict__ o16b,
                                          unsigned char* __restrict__ lds) {
  constexpr int KSTEPS = (OP == 0) ? 16 : 4;
  constexpr bool AFLT = (OP == 0) || (OP == 1);  // A is f32, cvt at write
  constexpr int LD = (OP == 0) ? 1024 : 256;     // B leading dim

  unsigned short* As0 = (unsigned short*)lds;          // 32x64 bf16 = 4 KB
  unsigned short* As1 = As0 + 2048;
  unsigned short* Bs0 = As0 + 4096;                    // 256x64 bf16 = 32 KB
  unsigned short* Bs1 = Bs0 + 16384;

  int tid = threadIdx.x;
  int wid = tid >> 6, lane = tid & 63, lg = lane >> 4, lc = lane & 15;

  // staging addressing
  int arow = tid >> 3, ac = tid & 7;                   // A: 1 chunk/thread
  int adst = arow * 64 + ((ac ^ (arow & 7)) * 8);
  const unsigned short* Aus = nullptr; const float* Afs = nullptr;
  int tok4[4] = {0, 0, 0, 0};
  const float* kvxb = nullptr;
  float amul = 1.0f;
  if constexpr (OP == 0) {
    // gathered conv input: row -> (b, sy, sx); 4 source tokens, one per 2x2 slot
    int grow = rowbase + arow;
    int bb = grow >> 10, sp = grow & 1023, sy = sp >> 5, sx = sp & 31;
#pragma unroll
    for (int s = 0; s < 4; ++s) {
      int yy = 2 * sy + (s >> 1), xx = 2 * sx + (s & 1);
      tok4[s] = idxt[bb * 4096 + yy * 64 + xx];
    }
    kvxb = (const float*)Ap + (size_t)bb * 2048 * 256 + ac * 8;
    amul = 1.0f / 1.000001f;
  } else if constexpr (OP == 1) {
    Afs = (const float*)Ap + (size_t)(rowbase + arow) * 256 + ac * 8;
  } else {
    Aus = (const unsigned short*)Ap + (size_t)(rowbase + arow) * 256 + ac * 8;
  }
  int brg = tid >> 3, bc = tid & 7;                    // B: 8 rows/thread (stride 32)
  const unsigned short* Bsrc = Bp + (size_t)(ntbase + brg) * LD + bc * 8;
  int bdst = brg * 64 + ((bc ^ (brg & 7)) * 8);

  s16x8 ra; f32x4 ra0, ra1; s16x8 rb[8];
  f32x4 acc[2][4] = {};

  // A-load issue helper (f32 paths)
  auto a_issue = [&](int ko) {
    if constexpr (OP == 0) {
      const float* p = kvxb + (size_t)tok4[ko >> 8] * 256 + (ko & 255);
      ra0 = *(const f32x4*)(p);
      ra1 = *(const f32x4*)(p + 4);
    } else if constexpr (OP == 1) {
      ra0 = *(const f32x4*)(Afs + ko);
      ra1 = *(const f32x4*)(Afs + ko + 4);
    } else {
      ra = *(const s16x8*)(Aus + ko);
    }
  };
  auto a_write = [&](unsigned short* An) {
    if constexpr (AFLT) {
      PKU aw;
      aw.u[0] = cvt_pk_bf16(ra0[0] * amul, ra0[1] * amul);
      aw.u[1] = cvt_pk_bf16(ra0[2] * amul, ra0[3] * amul);
      aw.u[2] = cvt_pk_bf16(ra1[0] * amul, ra1[1] * amul);
      aw.u[3] = cvt_pk_bf16(ra1[2] * amul, ra1[3] * amul);
      *(s16x8*)(An + adst) = aw.s;
    } else {
      *(s16x8*)(An + adst) = ra;
    }
  };

  // prologue: stage step 0
  {
    a_issue(0);
#pragma unroll
    for (int i = 0; i < 8; ++i) rb[i] = *(const s16x8*)(Bsrc + (size_t)i * 32 * LD);
    a_write(As0);
#pragma unroll
    for (int i = 0; i < 8; ++i) *(s16x8*)(Bs0 + bdst + i * 2048) = rb[i];
  }
  __syncthreads();

#pragma unroll 2
  for (int it = 0; it < KSTEPS - 1; ++it) {
    const unsigned short* Ac = (it & 1) ? As1 : As0;
    const unsigned short* Bc = (it & 1) ? Bs1 : Bs0;
    unsigned short* An = (it & 1) ? As0 : As1;
    unsigned short* Bn = (it & 1) ? Bs0 : Bs1;
    int ko = (it + 1) * 64;
    // issue next-step loads
    a_issue(ko);
#pragma unroll
    for (int i = 0; i < 8; ++i) rb[i] = *(const s16x8*)(Bsrc + (size_t)i * 32 * LD + ko);
    // compute on current buffer
#pragma unroll
    for (int kc = 0; kc < 2; ++kc) {
      int swz = ((kc * 4 + lg) ^ (lc & 7)) * 8;
      ABF a0, a1;
      a0.s = *(const s16x8*)(Ac + lc * 64 + swz);
      a1.s = *(const s16x8*)(Ac + (16 + lc) * 64 + swz);
#pragma unroll
      for (int cf = 0; cf < 4; ++cf) {
        ABF bf; bf.s = *(const s16x8*)(Bc + (wid * 64 + cf * 16 + lc) * 64 + swz);
        acc[0][cf] = __builtin_amdgcn_mfma_f32_16x16x32_bf16(a0.v, bf.v, acc[0][cf], 0, 0, 0);
        acc[1][cf] = __builtin_amdgcn_mfma_f32_16x16x32_bf16(a1.v, bf.v, acc[1][cf], 0, 0, 0);
      }
    }
    // write staged regs to the other buffer
    a_write(An);
#pragma unroll
    for (int i = 0; i < 8; ++i) *(s16x8*)(Bn + bdst + i * 2048) = rb[i];
    __syncthreads();
  }
  // last step compute
  {
    const unsigned short* Ac = ((KSTEPS - 1) & 1) ? As1 : As0;
    const unsigned short* Bc = ((KSTEPS - 1) & 1) ? Bs1 : Bs0;
#pragma unroll
    for (int kc = 0; kc < 2; ++kc) {
      int swz = ((kc * 4 + lg) ^ (lc & 7)) * 8;
      ABF a0, a1;
      a0.s = *(const s16x8*)(Ac + lc * 64 + swz);
      a1.s = *(const s16x8*)(Ac + (16 + lc) * 64 + swz);
#pragma unroll
      for (int cf = 0; cf < 4; ++cf) {
        ABF bf; bf.s = *(const s16x8*)(Bc + (wid * 64 + cf * 16 + lc) * 64 + swz);
        acc[0][cf] = __builtin_amdgcn_mfma_f32_16x16x32_bf16(a0.v, bf.v, acc[0][cf], 0, 0, 0);
        acc[1][cf] = __builtin_amdgcn_mfma_f32_16x16x32_bf16(a1.v, bf.v, acc[1][cf], 0, 0, 0);
      }
    }
  }
  __syncthreads();

  // ---- epilogues ----
  if constexpr (OP == 1) {
    const float qs = 0.17677669529663687f * LOG2E;
#pragma unroll
    for (int rf = 0; rf < 2; ++rf)
#pragma unroll
      for (int cf = 0; cf < 4; ++cf) {
        int col = wid * 64 + cf * 16 + lc;
        int h = col >> 5, d = col & 31;
#pragma unroll
        for (int r = 0; r < 4; ++r) {
          int row = rowbase + rf * 16 + lg * 4 + r;
          int b = row >> 11, n = row & 2047;
          o16[(size_t)((b * 8 + h) * 2048 + n) * 32 + d] = f2bf(acc[rf][cf][r] * qs);
        }
      }
  } else if constexpr (OP == 2) {
#pragma unroll
    for (int rf = 0; rf < 2; ++rf)
#pragma unroll
      for (int cf = 0; cf < 4; ++cf) {
        int j = ntbase + wid * 64 + cf * 16 + lc;
        int sflag = j >> 8, h = (j >> 5) & 7, d = j & 31;
#pragma unroll
        for (int r = 0; r < 4; ++r) {
          int row = rowbase + rf * 16 + lg * 4 + r;
          int b = row >> 10, m = row & 1023;
          unsigned short v = f2bf(acc[rf][cf][r]);
          if (sflag == 0) o16[(size_t)((b * 8 + h) * 1024 + m) * 32 + d] = v;
          else            o16b[(size_t)((b * 8 + h) * 32 + d) * 1024 + m] = v;
        }
      }
  } else if constexpr (OP == 3) {
#pragma unroll
    for (int rf = 0; rf < 2; ++rf)
#pragma unroll
      for (int cf = 0; cf < 4; ++cf) {
        int col = wid * 64 + cf * 16 + lc;
        float bv = bias[col];
#pragma unroll
        for (int r = 0; r < 4; ++r) {
          int row = rowbase + rf * 16 + lg * 4 + r;
          of32[(size_t)row * 256 + col] = acc[rf][cf][r] + bv;
        }
      }
  } else {
    // conv: bias + LayerNorm over 256 cols, write kv_ln bf16. srow aliases staging LDS.
    float* srow = (float*)lds;  // [32][260]
#pragma unroll
    for (int rf = 0; rf < 2; ++rf)
#pragma unroll
      for (int cf = 0; cf < 4; ++cf) {
        int col = wid * 64 + cf * 16 + lc;
        float bv = bias[col];
#pragma unroll
        for (int r = 0; r < 4; ++r)
          srow[(rf * 16 + lg * 4 + r) * 260 + col] = acc[rf][cf][r] + bv;
      }
    __syncthreads();
#pragma unroll
    for (int s = 0; s < 2; ++s) {
      int r = s * 16 + (tid >> 4), c16 = tid & 15;
      float vals[16];
      float sm = 0.f, ss = 0.f;
#pragma unroll
      for (int i = 0; i < 16; ++i) {
        float v = srow[r * 260 + c16 * 16 + i];
        vals[i] = v; sm += v; ss += v * v;
      }
#pragma unroll
      for (int m = 1; m < 16; m <<= 1) {
        sm += __shfl_xor(sm, m, 64);
        ss += __shfl_xor(ss, m, 64);
      }
      float mu = sm * (1.0f / 256.0f);
      float var = ss * (1.0f / 256.0f) - mu * mu;
      float rstd = rsqrtf(var + 1e-5f);
      s16x8 w0, w1;
#pragma unroll
      for (int i = 0; i < 8; ++i) {
        int c = c16 * 16 + i;
        w0[i] = (short)f2bf((vals[i] - mu) * rstd * lnw[c] + lnb[c]);
      }
#pragma unroll
      for (int i = 0; i < 8; ++i) {
        int c = c16 * 16 + 8 + i;
        w1[i] = (short)f2bf((vals[8 + i] - mu) * rstd * lnw[c] + lnb[c]);
      }
      *(s16x8*)(o16 + (size_t)(rowbase + r) * 256 + c16 * 16) = w0;
      *(s16x8*)(o16 + (size_t)(rowbase + r) * 256 + c16 * 16 + 8) = w1;
    }
  }
}

// ---------------- GEMM kernel wrappers ----------------

__global__ __launch_bounds__(256, 2) void k_qc(const float* __restrict__ q_x,
                                               const unsigned short* __restrict__ q_wb,
                                               unsigned short* __restrict__ q_s,
                                               const float* __restrict__ kv_x,
                                               const int* __restrict__ idx_token,
                                               const unsigned short* __restrict__ w4t,
                                               const float* __restrict__ sr_b,
                                               const float* __restrict__ ln_w,
                                               const float* __restrict__ ln_b,
                                               unsigned short* __restrict__ kv_ln) {
  __shared__ __align__(16) unsigned char lds[73728];
  int bid = blockIdx.x;
  if (bid < 256)
    gemm_tile<0>(bid * 32, 0, kv_x, w4t, idx_token, sr_b, ln_w, ln_b, kv_ln, nullptr, nullptr, lds);
  else
    gemm_tile<1>((bid - 256) * 32, 0, q_x, q_wb, nullptr, nullptr, nullptr, nullptr, q_s, nullptr, nullptr, lds);
}

__global__ __launch_bounds__(256, 2) void k_kvproj(const unsigned short* __restrict__ kv_ln,
                                                   const unsigned short* __restrict__ kv_wb,
                                                   unsigned short* __restrict__ kmat,
                                                   unsigned short* __restrict__ vt) {
  __shared__ __align__(16) unsigned char lds[73728];
  int bid = blockIdx.x;
  gemm_tile<2>((bid & 255) * 32, (bid >> 8) * 256, kv_ln, kv_wb, nullptr, nullptr, nullptr, nullptr,
               kmat, nullptr, vt, lds);
}

__global__ __launch_bounds__(256, 2) void k_proj(const unsigned short* __restrict__ xat,
                                                 const unsigned short* __restrict__ p_wb,
                                                 const float* __restrict__ pb,
                                                 float* __restrict__ out) {
  __shared__ __align__(16) unsigned char lds[73728];
  gemm_tile<3>(blockIdx.x * 32, 0, xat, p_wb, nullptr, pb, nullptr, nullptr, nullptr, out, nullptr, lds);
}

// ---------------- flash attention: r6-proven version, byte-identical ----------------
// grid 1024 blocks (XCD-swizzled), 4 waves x 32 q-rows each. Max-free log2 softmax.
__global__ __launch_bounds__(256, 4) void k_attn(const unsigned short* __restrict__ q_s,
                                                 const unsigned short* __restrict__ kmat,
                                                 const unsigned short* __restrict__ vt,
                                                 const float* __restrict__ conf,
                                                 unsigned short* __restrict__ xat) {
  __shared__ __align__(16) unsigned short Kl[2][2048];  // [64 rows][32 d], chunk^(row&3) swizzle
  __shared__ __align__(16) unsigned short Vl[2][2048];  // [32 d][64 k],   chunk^(d&7)  swizzle
  __shared__ __align__(16) float Cf[2][64];
  __shared__ __align__(16) unsigned short p_lds[8192];  // [4 wid][2 g][16 q][64 k]

  int tid = threadIdx.x;
  int wid = tid >> 6, lane = tid & 63, lg = lane >> 4, lc = lane & 15;
  // XCD swizzle: 8 heads per XCD, all 16 q-tiles of a head on the same XCD
  int bid = blockIdx.x;
  int xcd = bid & 7, slot = bid >> 3;
  int bh = xcd * 8 + (slot >> 4);
  int qt = slot & 15;
  int b = bh >> 3, h = bh & 7;
  int qbase = qt * 128 + wid * 32;

  ABF qf[2];
  qf[0].s = *(const s16x8*)(q_s + (size_t)(bh * 2048 + qbase + lc) * 32 + lg * 8);
  qf[1].s = *(const s16x8*)(q_s + (size_t)(bh * 2048 + qbase + 16 + lc) * 32 + lg * 8);

  ABF ones;
#pragma unroll
  for (int i = 0; i < 8; ++i) ones.s[i] = (short)0x3F80;  // bf16 1.0

  f32x4 oacc[2][2] = {};
  f32x4 lacc[2] = {};

  // ---- staging addressing (per thread) ----
  int krow = tid >> 2, kch = tid & 3;
  const unsigned short* kgp = kmat + (size_t)bh * 32768 + krow * 32 + kch * 8;
  int kdst = krow * 32 + ((kch ^ (krow & 3)) * 8);
  int vd = tid >> 3, vch = tid & 7;
  const unsigned short* vgp = vt + (size_t)bh * 32768 + vd * 1024 + vch * 8;
  int vdst = vd * 64 + ((vch ^ (vd & 7)) * 8);
  const float* cgp = conf + b * 1024 + (tid & 15) * 4;

  // ---- compute-side LDS offsets (shorts/floats) ----
  int kf_off[4];
#pragma unroll
  for (int t = 0; t < 4; ++t) kf_off[t] = (t * 16 + lc) * 32 + ((lg ^ (lc & 3)) * 8);
  int vb_off[2][2];
#pragma unroll
  for (int c = 0; c < 2; ++c)
#pragma unroll
    for (int dh = 0; dh < 2; ++dh)
      vb_off[c][dh] = (dh * 16 + lc) * 64 + (((4 * c + lg) ^ (lc & 7)) * 8);
  int c4_off = lg * 4;

  // p_lds swizzled offsets: row = lc (128B), slot' = slot ^ (lc&7)
  unsigned short* ldsrow = p_lds + (wid * 2 * 16 + lc) * 64;
  int sw = lc & 7;
  int w_off[4], r_off[2];
#pragma unroll
  for (int t = 0; t < 4; ++t)
    w_off[t] = (((2 * t + (lg >> 1)) ^ sw) << 3) + ((lg & 1) << 2);
#pragma unroll
  for (int p = 0; p < 2; ++p)
    r_off[p] = ((p * 4 + lg) ^ sw) << 3;

  // ---- stage tile 0 ----
  s16x8 pk = *(const s16x8*)(kgp);
  s16x8 pv = *(const s16x8*)(vgp);
  f32x4 pc;
  if (tid < 16) pc = *(const f32x4*)(cgp);
  *(s16x8*)(&Kl[0][kdst]) = pk;
  *(s16x8*)(&Vl[0][vdst]) = pv;
  if (tid < 16) *(f32x4*)(&Cf[0][tid * 4]) = pc;
  __syncthreads();

#pragma unroll 2
  for (int it = 0; it < 16; ++it) {
    const int buf = it & 1;
    if (it < 15) {  // prefetch next tile into registers (latency hides under compute)
      pk = *(const s16x8*)(kgp + (it + 1) * 2048);
      pv = *(const s16x8*)(vgp + (it + 1) * 64);
      if (tid < 16) pc = *(const f32x4*)(cgp + (it + 1) * 64);
    }
    // ---- compute on buf ----
    ABF kf[4]; f32x4 c4[4];
#pragma unroll
    for (int t = 0; t < 4; ++t) {
      kf[t].s = *(const s16x8*)(&Kl[buf][kf_off[t]]);
      c4[t] = *(const f32x4*)(&Cf[buf][t * 16 + c4_off]);
    }
    ABF vb[2][2];
#pragma unroll
    for (int c = 0; c < 2; ++c)
#pragma unroll
      for (int dh = 0; dh < 2; ++dh)
        vb[c][dh].s = *(const s16x8*)(&Vl[buf][vb_off[c][dh]]);

    // swapped QK^T: lane holds q=lc, k rows
#pragma unroll
    for (int g = 0; g < 2; ++g) {
      unsigned short* lrow = ldsrow + g * 1024;
#pragma unroll
      for (int t = 0; t < 4; ++t) {
        f32x4 st = __builtin_amdgcn_mfma_f32_16x16x32_bf16(kf[t].v, qf[g].v, c4[t], 0, 0, 0);
        f32x4 pt;
        pt[0] = __builtin_amdgcn_exp2f(st[0]);
        pt[1] = __builtin_amdgcn_exp2f(st[1]);
        pt[2] = __builtin_amdgcn_exp2f(st[2]);
        pt[3] = __builtin_amdgcn_exp2f(st[3]);
        u32x2 w;
        w.x = cvt_pk_bf16(pt[0], pt[1]);
        w.y = cvt_pk_bf16(pt[2], pt[3]);
        *(u32x2*)(lrow + w_off[t]) = w;
      }
    }
    // PV + row-sum via ones-MFMA
#pragma unroll
    for (int g = 0; g < 2; ++g) {
      unsigned short* lrow = ldsrow + g * 1024;
      ABF pa0, pa1;
      pa0.s = *(const s16x8*)(lrow + r_off[0]);
      pa1.s = *(const s16x8*)(lrow + r_off[1]);
      oacc[g][0] = __builtin_amdgcn_mfma_f32_16x16x32_bf16(pa0.v, vb[0][0].v, oacc[g][0], 0, 0, 0);
      oacc[g][1] = __builtin_amdgcn_mfma_f32_16x16x32_bf16(pa0.v, vb[0][1].v, oacc[g][1], 0, 0, 0);
      lacc[g]    = __builtin_amdgcn_mfma_f32_16x16x32_bf16(pa0.v, ones.v,     lacc[g],    0, 0, 0);
      oacc[g][0] = __builtin_amdgcn_mfma_f32_16x16x32_bf16(pa1.v, vb[1][0].v, oacc[g][0], 0, 0, 0);
      oacc[g][1] = __builtin_amdgcn_mfma_f32_16x16x32_bf16(pa1.v, vb[1][1].v, oacc[g][1], 0, 0, 0);
      lacc[g]    = __builtin_amdgcn_mfma_f32_16x16x32_bf16(pa1.v, ones.v,     lacc[g],    0, 0, 0);
    }
    // ---- write prefetched tile to the other buffer ----
    if (it < 15) {
      *(s16x8*)(&Kl[buf ^ 1][kdst]) = pk;
      *(s16x8*)(&Vl[buf ^ 1][vdst]) = pv;
      if (tid < 16) *(f32x4*)(&Cf[buf ^ 1][tid * 4]) = pc;
    }
    __syncthreads();
  }

#pragma unroll
  for (int g = 0; g < 2; ++g) {
#pragma unroll
    for (int r = 0; r < 4; ++r) {
      float inv = 1.0f / lacc[g][r];
      int q = qbase + g * 16 + lg * 4 + r;
      xat[(size_t)(b * 2048 + q) * 256 + h * 32 + lc] = f2bf(oacc[g][0][r] * inv);
      xat[(size_t)(b * 2048 + q) * 256 + h * 32 + 16 + lc] = f2bf(oacc[g][1][r] * inv);
    }
  }
}

// ---------------- launch ----------------

extern "C" void kernel_launch(void* const* d_in, const int* in_sizes, int n_in,
                              void* d_out, int out_size, void* d_ws, size_t ws_size,
                              hipStream_t stream) {
  (void)in_sizes; (void)n_in; (void)out_size; (void)ws_size;
  const float* q_x         = (const float*)d_in[0];
  const float* kv_x        = (const float*)d_in[1];
  const float* token_score = (const float*)d_in[2];
  const int*   idx_token   = (const int*)d_in[3];
  const float* q_w         = (const float*)d_in[4];
  const float* kv_w        = (const float*)d_in[5];
  const float* proj_w      = (const float*)d_in[6];
  const float* proj_b      = (const float*)d_in[7];
  const float* sr_w        = (const float*)d_in[8];
  const float* sr_b        = (const float*)d_in[9];
  const float* ln_w        = (const float*)d_in[10];
  const float* ln_b        = (const float*)d_in[11];
  float* out = (float*)d_out;

  char* ws = (char*)d_ws;
  unsigned short* q_s   = (unsigned short*)(ws + 0);          // 64*2048*32  bf16 = 8 MB
  unsigned short* xat   = (unsigned short*)(ws + 8388608);    // 16384*256   bf16 = 8 MB
  unsigned short* w4t   = (unsigned short*)(ws + 25165824);   // 256*1024    bf16
  unsigned short* kv_ln = (unsigned short*)(ws + 25690112);   // 8192*256    bf16
  unsigned short* kmat  = (unsigned short*)(ws + 29884416);   // 64*1024*32  bf16
  unsigned short* vt    = (unsigned short*)(ws + 34078720);   // 64*32*1024  bf16
  float*          confp = (float*)(ws + 38273024);            // 8*1024      f32
  unsigned short* q_wb  = (unsigned short*)(ws + 46694400);   // 256*256     bf16
  unsigned short* kv_wb = (unsigned short*)(ws + 46825472);   // 512*256     bf16
  unsigned short* p_wb  = (unsigned short*)(ws + 47087616);   // 256*256     bf16

  k_pre<<<dim3(2080), dim3(256), 0, stream>>>(q_w, kv_w, proj_w, sr_w, token_score, idx_token,
                                              q_wb, kv_wb, p_wb, w4t, confp);
  k_qc<<<dim3(768), dim3(256), 0, stream>>>(q_x, q_wb, q_s, kv_x, idx_token, w4t,
                                            sr_b, ln_w, ln_b, kv_ln);
  k_kvproj<<<dim3(512), dim3(256), 0, stream>>>(kv_ln, kv_wb, kmat, vt);
  k_attn<<<dim3(1024), dim3(256), 0, stream>>>(q_s, kmat, vt, confp, xat);
  k_proj<<<dim3(512), dim3(256), 0, stream>>>(xat, p_wb, proj_b, out);
}

// Round 10
// 76.725 us; speedup vs baseline: 1.7556x; 1.0386x over previous
//
#include <hip/hip_runtime.h>

#define LOG2E 1.4426950408889634f

typedef float f32x4 __attribute__((ext_vector_type(4)));
typedef short s16x4 __attribute__((ext_vector_type(4)));
typedef short s16x8 __attribute__((ext_vector_type(8)));
typedef __bf16 bf16x8 __attribute__((ext_vector_type(8)));
typedef unsigned int u32x2 __attribute__((ext_vector_type(2)));

union ABF { s16x8 s; bf16x8 v; };
union PKU { unsigned int u[4]; s16x8 s; bf16x8 v; };

__device__ __forceinline__ unsigned short f2bf(float f) {
  unsigned int u = __builtin_bit_cast(unsigned int, f);
  u += 0x7fffu + ((u >> 16) & 1u);
  return (unsigned short)(u >> 16);
}

__device__ __forceinline__ unsigned int cvt_pk_bf16(float a, float b) {
  unsigned int r;
  asm("v_cvt_pk_bf16_f32 %0, %1, %2" : "=v"(r) : "v"(a), "v"(b));
  return r;  // low16 = bf16(a), high16 = bf16(b)
}

// ---------------- k_pre: weight converts + conv-weight repack + conf ----------------

__global__ __launch_bounds__(256) void k_pre(const float* __restrict__ q_w,
                                             const float* __restrict__ kv_w,
                                             const float* __restrict__ proj_w,
                                             const float* __restrict__ sr_w,
                                             const float* __restrict__ token_score,
                                             const int* __restrict__ idx_token,
                                             unsigned short* __restrict__ q_wb,
                                             unsigned short* __restrict__ kv_wb,
                                             unsigned short* __restrict__ p_wb,
                                             unsigned short* __restrict__ w4t,
                                             float* __restrict__ conf) {
  int bid = blockIdx.x, t = threadIdx.x;
  if (bid < 256) { int i = bid * 256 + t; q_wb[i] = f2bf(q_w[i]); return; }
  if (bid < 768) { int i = (bid - 256) * 256 + t; kv_wb[i] = f2bf(kv_w[i]); return; }
  if (bid < 1024) { int i = (bid - 768) * 256 + t; p_wb[i] = f2bf(proj_w[i]); return; }
  if (bid < 2048) {
    // w4t[co][k], k = (dh*2+dw)*256 + ci ; from sr_w[co][ci][dh][dw]
    int idx = (bid - 1024) * 256 + t;
    int co = idx >> 10, k = idx & 1023;
    int slot = k >> 8, ci = k & 255;
    int dh = slot >> 1, dw = slot & 1;
    w4t[idx] = f2bf(sr_w[((co * 256 + ci) * 2 + dh) * 2 + dw]);
    return;
  }
  // conf[b][m] = log2e * mean_{2x2}(token_score gathered) / 1.000001
  int i = (bid - 2048) * 256 + t;  // B*1024 = 8192
  int b = i >> 10, m = i & 1023;
  int h = m >> 5, w = m & 31;
  float s = 0.f;
#pragma unroll
  for (int dh = 0; dh < 2; ++dh)
#pragma unroll
    for (int dw = 0; dw < 2; ++dw) {
      int j = (2 * h + dh) * 64 + (2 * w + dw);
      s += token_score[b * 2048 + idx_token[b * 4096 + j]];
    }
  conf[i] = s * 0.25f * (1.0f / 1.000001f) * LOG2E;
}

// ---------------- unified 32x256 LDS-staged GEMM tile ----------------
// OP: 0=conv(+bias+LN->kv_ln, A gathered from kv_x f32), 1=qproj(A=q_x f32),
//     2=kvproj(->kmat/vt), 3=proj(+bias->f32)
// Tile: 32 rows x 256 cols, BK=64, 4 waves. A,B double-buffered in LDS,
// chunk^(row&7) swizzle; reg-staged global->LDS (issue-early, cvt+write-late).

template<int OP>
__device__ __forceinline__ void gemm_tile(int rowbase, int ntbase,
                                          const void* __restrict__ Ap,
                                          const unsigned short* __restrict__ Bp,
                                          const int* __restrict__ idxt,
                                          const float* __restrict__ bias,
                                          const float* __restrict__ lnw,
                                          const float* __restrict__ lnb,
                                          unsigned short* __restrict__ o16,
                                          float* __restrict__ of32,
                                          unsigned short* __restrict__ o16b,
                                          unsigned char* __restrict__ lds) {
  constexpr int KSTEPS = (OP == 0) ? 16 : 4;
  constexpr bool AFLT = (OP == 0) || (OP == 1);  // A is f32, cvt at write
  constexpr int LD = (OP == 0) ? 1024 : 256;     // B leading dim

  unsigned short* As0 = (unsigned short*)lds;          // 32x64 bf16 = 4 KB
  unsigned short* As1 = As0 + 2048;
  unsigned short* Bs0 = As0 + 4096;                    // 256x64 bf16 = 32 KB
  unsigned short* Bs1 = Bs0 + 16384;

  int tid = threadIdx.x;
  int wid = tid >> 6, lane = tid & 63, lg = lane >> 4, lc = lane & 15;

  // staging addressing
  int arow = tid >> 3, ac = tid & 7;                   // A: 1 chunk/thread
  int adst = arow * 64 + ((ac ^ (arow & 7)) * 8);
  const unsigned short* Aus = nullptr; const float* Afs = nullptr;
  int tok4[4] = {0, 0, 0, 0};
  const float* kvxb = nullptr;
  float amul = 1.0f;
  if constexpr (OP == 0) {
    // gathered conv input: row -> (b, sy, sx); 4 source tokens, one per 2x2 slot
    int grow = rowbase + arow;
    int bb = grow >> 10, sp = grow & 1023, sy = sp >> 5, sx = sp & 31;
#pragma unroll
    for (int s = 0; s < 4; ++s) {
      int yy = 2 * sy + (s >> 1), xx = 2 * sx + (s & 1);
      tok4[s] = idxt[bb * 4096 + yy * 64 + xx];
    }
    kvxb = (const float*)Ap + (size_t)bb * 2048 * 256 + ac * 8;
    amul = 1.0f / 1.000001f;
  } else if constexpr (OP == 1) {
    Afs = (const float*)Ap + (size_t)(rowbase + arow) * 256 + ac * 8;
  } else {
    Aus = (const unsigned short*)Ap + (size_t)(rowbase + arow) * 256 + ac * 8;
  }
  int brg = tid >> 3, bc = tid & 7;                    // B: 8 rows/thread (stride 32)
  const unsigned short* Bsrc = Bp + (size_t)(ntbase + brg) * LD + bc * 8;
  int bdst = brg * 64 + ((bc ^ (brg & 7)) * 8);

  s16x8 ra; f32x4 ra0, ra1; s16x8 rb[8];
  f32x4 acc[2][4] = {};

  // A-load issue helper (f32 paths)
  auto a_issue = [&](int ko) {
    if constexpr (OP == 0) {
      const float* p = kvxb + (size_t)tok4[ko >> 8] * 256 + (ko & 255);
      ra0 = *(const f32x4*)(p);
      ra1 = *(const f32x4*)(p + 4);
    } else if constexpr (OP == 1) {
      ra0 = *(const f32x4*)(Afs + ko);
      ra1 = *(const f32x4*)(Afs + ko + 4);
    } else {
      ra = *(const s16x8*)(Aus + ko);
    }
  };
  auto a_write = [&](unsigned short* An) {
    if constexpr (AFLT) {
      PKU aw;
      aw.u[0] = cvt_pk_bf16(ra0[0] * amul, ra0[1] * amul);
      aw.u[1] = cvt_pk_bf16(ra0[2] * amul, ra0[3] * amul);
      aw.u[2] = cvt_pk_bf16(ra1[0] * amul, ra1[1] * amul);
      aw.u[3] = cvt_pk_bf16(ra1[2] * amul, ra1[3] * amul);
      *(s16x8*)(An + adst) = aw.s;
    } else {
      *(s16x8*)(An + adst) = ra;
    }
  };

  // prologue: stage step 0
  {
    a_issue(0);
#pragma unroll
    for (int i = 0; i < 8; ++i) rb[i] = *(const s16x8*)(Bsrc + (size_t)i * 32 * LD);
    a_write(As0);
#pragma unroll
    for (int i = 0; i < 8; ++i) *(s16x8*)(Bs0 + bdst + i * 2048) = rb[i];
  }
  __syncthreads();

#pragma unroll 2
  for (int it = 0; it < KSTEPS - 1; ++it) {
    const unsigned short* Ac = (it & 1) ? As1 : As0;
    const unsigned short* Bc = (it & 1) ? Bs1 : Bs0;
    unsigned short* An = (it & 1) ? As0 : As1;
    unsigned short* Bn = (it & 1) ? Bs0 : Bs1;
    int ko = (it + 1) * 64;
    // issue next-step loads
    a_issue(ko);
#pragma unroll
    for (int i = 0; i < 8; ++i) rb[i] = *(const s16x8*)(Bsrc + (size_t)i * 32 * LD + ko);
    // compute on current buffer
#pragma unroll
    for (int kc = 0; kc < 2; ++kc) {
      int swz = ((kc * 4 + lg) ^ (lc & 7)) * 8;
      ABF a0, a1;
      a0.s = *(const s16x8*)(Ac + lc * 64 + swz);
      a1.s = *(const s16x8*)(Ac + (16 + lc) * 64 + swz);
#pragma unroll
      for (int cf = 0; cf < 4; ++cf) {
        ABF bf; bf.s = *(const s16x8*)(Bc + (wid * 64 + cf * 16 + lc) * 64 + swz);
        acc[0][cf] = __builtin_amdgcn_mfma_f32_16x16x32_bf16(a0.v, bf.v, acc[0][cf], 0, 0, 0);
        acc[1][cf] = __builtin_amdgcn_mfma_f32_16x16x32_bf16(a1.v, bf.v, acc[1][cf], 0, 0, 0);
      }
    }
    // write staged regs to the other buffer
    a_write(An);
#pragma unroll
    for (int i = 0; i < 8; ++i) *(s16x8*)(Bn + bdst + i * 2048) = rb[i];
    __syncthreads();
  }
  // last step compute
  {
    const unsigned short* Ac = ((KSTEPS - 1) & 1) ? As1 : As0;
    const unsigned short* Bc = ((KSTEPS - 1) & 1) ? Bs1 : Bs0;
#pragma unroll
    for (int kc = 0; kc < 2; ++kc) {
      int swz = ((kc * 4 + lg) ^ (lc & 7)) * 8;
      ABF a0, a1;
      a0.s = *(const s16x8*)(Ac + lc * 64 + swz);
      a1.s = *(const s16x8*)(Ac + (16 + lc) * 64 + swz);
#pragma unroll
      for (int cf = 0; cf < 4; ++cf) {
        ABF bf; bf.s = *(const s16x8*)(Bc + (wid * 64 + cf * 16 + lc) * 64 + swz);
        acc[0][cf] = __builtin_amdgcn_mfma_f32_16x16x32_bf16(a0.v, bf.v, acc[0][cf], 0, 0, 0);
        acc[1][cf] = __builtin_amdgcn_mfma_f32_16x16x32_bf16(a1.v, bf.v, acc[1][cf], 0, 0, 0);
      }
    }
  }
  __syncthreads();

  // ---- epilogues ----
  if constexpr (OP == 1) {
    const float qs = 0.17677669529663687f * LOG2E;
#pragma unroll
    for (int rf = 0; rf < 2; ++rf)
#pragma unroll
      for (int cf = 0; cf < 4; ++cf) {
        int col = wid * 64 + cf * 16 + lc;
        int h = col >> 5, d = col & 31;
#pragma unroll
        for (int r = 0; r < 4; ++r) {
          int row = rowbase + rf * 16 + lg * 4 + r;
          int b = row >> 11, n = row & 2047;
          o16[(size_t)((b * 8 + h) * 2048 + n) * 32 + d] = f2bf(acc[rf][cf][r] * qs);
        }
      }
  } else if constexpr (OP == 2) {
#pragma unroll
    for (int rf = 0; rf < 2; ++rf)
#pragma unroll
      for (int cf = 0; cf < 4; ++cf) {
        int j = ntbase + wid * 64 + cf * 16 + lc;
        int sflag = j >> 8, h = (j >> 5) & 7, d = j & 31;
        int row0 = rowbase + rf * 16 + lg * 4;
        int b = row0 >> 10, m0 = row0 & 1023;
        if (sflag == 0) {
#pragma unroll
          for (int r = 0; r < 4; ++r)
            o16[(size_t)((b * 8 + h) * 1024 + m0 + r) * 32 + d] = f2bf(acc[rf][cf][r]);
        } else {
          // vt: 4 consecutive m positions -> one 8B store
          s16x4 pack;
#pragma unroll
          for (int r = 0; r < 4; ++r) pack[r] = (short)f2bf(acc[rf][cf][r]);
          *(s16x4*)(o16b + (size_t)((b * 8 + h) * 32 + d) * 1024 + m0) = pack;
        }
      }
  } else if constexpr (OP == 3) {
#pragma unroll
    for (int rf = 0; rf < 2; ++rf)
#pragma unroll
      for (int cf = 0; cf < 4; ++cf) {
        int col = wid * 64 + cf * 16 + lc;
        float bv = bias[col];
#pragma unroll
        for (int r = 0; r < 4; ++r) {
          int row = rowbase + rf * 16 + lg * 4 + r;
          of32[(size_t)row * 256 + col] = acc[rf][cf][r] + bv;
        }
      }
  } else {
    // conv: bias + LayerNorm over 256 cols, write kv_ln bf16. srow aliases staging LDS.
    float* srow = (float*)lds;  // [32][260]
#pragma unroll
    for (int rf = 0; rf < 2; ++rf)
#pragma unroll
      for (int cf = 0; cf < 4; ++cf) {
        int col = wid * 64 + cf * 16 + lc;
        float bv = bias[col];
#pragma unroll
        for (int r = 0; r < 4; ++r)
          srow[(rf * 16 + lg * 4 + r) * 260 + col] = acc[rf][cf][r] + bv;
      }
    __syncthreads();
#pragma unroll
    for (int s = 0; s < 2; ++s) {
      int r = s * 16 + (tid >> 4), c16 = tid & 15;
      float vals[16];
      float sm = 0.f, ss = 0.f;
#pragma unroll
      for (int i = 0; i < 16; ++i) {
        float v = srow[r * 260 + c16 * 16 + i];
        vals[i] = v; sm += v; ss += v * v;
      }
#pragma unroll
      for (int m = 1; m < 16; m <<= 1) {
        sm += __shfl_xor(sm, m, 64);
        ss += __shfl_xor(ss, m, 64);
      }
      float mu = sm * (1.0f / 256.0f);
      float var = ss * (1.0f / 256.0f) - mu * mu;
      float rstd = rsqrtf(var + 1e-5f);
      s16x8 w0, w1;
#pragma unroll
      for (int i = 0; i < 8; ++i) {
        int c = c16 * 16 + i;
        w0[i] = (short)f2bf((vals[i] - mu) * rstd * lnw[c] + lnb[c]);
      }
#pragma unroll
      for (int i = 0; i < 8; ++i) {
        int c = c16 * 16 + 8 + i;
        w1[i] = (short)f2bf((vals[8 + i] - mu) * rstd * lnw[c] + lnb[c]);
      }
      *(s16x8*)(o16 + (size_t)(rowbase + r) * 256 + c16 * 16) = w0;
      *(s16x8*)(o16 + (size_t)(rowbase + r) * 256 + c16 * 16 + 8) = w1;
    }
  }
}

// ---------------- GEMM kernel wrappers ----------------

__global__ __launch_bounds__(256, 2) void k_qc(const float* __restrict__ q_x,
                                               const unsigned short* __restrict__ q_wb,
                                               unsigned short* __restrict__ q_s,
                                               const float* __restrict__ kv_x,
                                               const int* __restrict__ idx_token,
                                               const unsigned short* __restrict__ w4t,
                                               const float* __restrict__ sr_b,
                                               const float* __restrict__ ln_w,
                                               const float* __restrict__ ln_b,
                                               unsigned short* __restrict__ kv_ln) {
  __shared__ __align__(16) unsigned char lds[73728];
  int bid = blockIdx.x;
  if (bid < 256)
    gemm_tile<0>(bid * 32, 0, kv_x, w4t, idx_token, sr_b, ln_w, ln_b, kv_ln, nullptr, nullptr, lds);
  else
    gemm_tile<1>((bid - 256) * 32, 0, q_x, q_wb, nullptr, nullptr, nullptr, nullptr, q_s, nullptr, nullptr, lds);
}

__global__ __launch_bounds__(256, 2) void k_kvproj(const unsigned short* __restrict__ kv_ln,
                                                   const unsigned short* __restrict__ kv_wb,
                                                   unsigned short* __restrict__ kmat,
                                                   unsigned short* __restrict__ vt) {
  __shared__ __align__(16) unsigned char lds[73728];
  int bid = blockIdx.x;
  gemm_tile<2>((bid & 255) * 32, (bid >> 8) * 256, kv_ln, kv_wb, nullptr, nullptr, nullptr, nullptr,
               kmat, nullptr, vt, lds);
}

__global__ __launch_bounds__(256, 2) void k_proj(const unsigned short* __restrict__ xat,
                                                 const unsigned short* __restrict__ p_wb,
                                                 const float* __restrict__ pb,
                                                 float* __restrict__ out) {
  __shared__ __align__(16) unsigned char lds[73728];
  gemm_tile<3>(blockIdx.x * 32, 0, xat, p_wb, nullptr, pb, nullptr, nullptr, nullptr, out, nullptr, lds);
}

// ---------------- flash attention: r6/r9-proven version + setprio on PV cluster ----------------
// grid 1024 blocks (XCD-swizzled), 4 waves x 32 q-rows each. Max-free log2 softmax.
__global__ __launch_bounds__(256, 4) void k_attn(const unsigned short* __restrict__ q_s,
                                                 const unsigned short* __restrict__ kmat,
                                                 const unsigned short* __restrict__ vt,
                                                 const float* __restrict__ conf,
                                                 unsigned short* __restrict__ xat) {
  __shared__ __align__(16) unsigned short Kl[2][2048];  // [64 rows][32 d], chunk^(row&3) swizzle
  __shared__ __align__(16) unsigned short Vl[2][2048];  // [32 d][64 k],   chunk^(d&7)  swizzle
  __shared__ __align__(16) float Cf[2][64];
  __shared__ __align__(16) unsigned short p_lds[8192];  // [4 wid][2 g][16 q][64 k]

  int tid = threadIdx.x;
  int wid = tid >> 6, lane = tid & 63, lg = lane >> 4, lc = lane & 15;
  // XCD swizzle: 8 heads per XCD, all 16 q-tiles of a head on the same XCD
  int bid = blockIdx.x;
  int xcd = bid & 7, slot = bid >> 3;
  int bh = xcd * 8 + (slot >> 4);
  int qt = slot & 15;
  int b = bh >> 3, h = bh & 7;
  int qbase = qt * 128 + wid * 32;

  ABF qf[2];
  qf[0].s = *(const s16x8*)(q_s + (size_t)(bh * 2048 + qbase + lc) * 32 + lg * 8);
  qf[1].s = *(const s16x8*)(q_s + (size_t)(bh * 2048 + qbase + 16 + lc) * 32 + lg * 8);

  ABF ones;
#pragma unroll
  for (int i = 0; i < 8; ++i) ones.s[i] = (short)0x3F80;  // bf16 1.0

  f32x4 oacc[2][2] = {};
  f32x4 lacc[2] = {};

  // ---- staging addressing (per thread) ----
  int krow = tid >> 2, kch = tid & 3;
  const unsigned short* kgp = kmat + (size_t)bh * 32768 + krow * 32 + kch * 8;
  int kdst = krow * 32 + ((kch ^ (krow & 3)) * 8);
  int vd = tid >> 3, vch = tid & 7;
  const unsigned short* vgp = vt + (size_t)bh * 32768 + vd * 1024 + vch * 8;
  int vdst = vd * 64 + ((vch ^ (vd & 7)) * 8);
  const float* cgp = conf + b * 1024 + (tid & 15) * 4;

  // ---- compute-side LDS offsets (shorts/floats) ----
  int kf_off[4];
#pragma unroll
  for (int t = 0; t < 4; ++t) kf_off[t] = (t * 16 + lc) * 32 + ((lg ^ (lc & 3)) * 8);
  int vb_off[2][2];
#pragma unroll
  for (int c = 0; c < 2; ++c)
#pragma unroll
    for (int dh = 0; dh < 2; ++dh)
      vb_off[c][dh] = (dh * 16 + lc) * 64 + (((4 * c + lg) ^ (lc & 7)) * 8);
  int c4_off = lg * 4;

  // p_lds swizzled offsets: row = lc (128B), slot' = slot ^ (lc&7)
  unsigned short* ldsrow = p_lds + (wid * 2 * 16 + lc) * 64;
  int sw = lc & 7;
  int w_off[4], r_off[2];
#pragma unroll
  for (int t = 0; t < 4; ++t)
    w_off[t] = (((2 * t + (lg >> 1)) ^ sw) << 3) + ((lg & 1) << 2);
#pragma unroll
  for (int p = 0; p < 2; ++p)
    r_off[p] = ((p * 4 + lg) ^ sw) << 3;

  // ---- stage tile 0 ----
  s16x8 pk = *(const s16x8*)(kgp);
  s16x8 pv = *(const s16x8*)(vgp);
  f32x4 pc;
  if (tid < 16) pc = *(const f32x4*)(cgp);
  *(s16x8*)(&Kl[0][kdst]) = pk;
  *(s16x8*)(&Vl[0][vdst]) = pv;
  if (tid < 16) *(f32x4*)(&Cf[0][tid * 4]) = pc;
  __syncthreads();

#pragma unroll 2
  for (int it = 0; it < 16; ++it) {
    const int buf = it & 1;
    if (it < 15) {  // prefetch next tile into registers (latency hides under compute)
      pk = *(const s16x8*)(kgp + (it + 1) * 2048);
      pv = *(const s16x8*)(vgp + (it + 1) * 64);
      if (tid < 16) pc = *(const f32x4*)(cgp + (it + 1) * 64);
    }
    // ---- compute on buf ----
    ABF kf[4]; f32x4 c4[4];
#pragma unroll
    for (int t = 0; t < 4; ++t) {
      kf[t].s = *(const s16x8*)(&Kl[buf][kf_off[t]]);
      c4[t] = *(const f32x4*)(&Cf[buf][t * 16 + c4_off]);
    }
    ABF vb[2][2];
#pragma unroll
    for (int c = 0; c < 2; ++c)
#pragma unroll
      for (int dh = 0; dh < 2; ++dh)
        vb[c][dh].s = *(const s16x8*)(&Vl[buf][vb_off[c][dh]]);

    // swapped QK^T: lane holds q=lc, k rows
#pragma unroll
    for (int g = 0; g < 2; ++g) {
      unsigned short* lrow = ldsrow + g * 1024;
#pragma unroll
      for (int t = 0; t < 4; ++t) {
        f32x4 st = __builtin_amdgcn_mfma_f32_16x16x32_bf16(kf[t].v, qf[g].v, c4[t], 0, 0, 0);
        f32x4 pt;
        pt[0] = __builtin_amdgcn_exp2f(st[0]);
        pt[1] = __builtin_amdgcn_exp2f(st[1]);
        pt[2] = __builtin_amdgcn_exp2f(st[2]);
        pt[3] = __builtin_amdgcn_exp2f(st[3]);
        u32x2 w;
        w.x = cvt_pk_bf16(pt[0], pt[1]);
        w.y = cvt_pk_bf16(pt[2], pt[3]);
        *(u32x2*)(lrow + w_off[t]) = w;
      }
    }
    // PV + row-sum via ones-MFMA (pure-MFMA cluster -> T5 setprio)
    __builtin_amdgcn_s_setprio(1);
#pragma unroll
    for (int g = 0; g < 2; ++g) {
      unsigned short* lrow = ldsrow + g * 1024;
      ABF pa0, pa1;
      pa0.s = *(const s16x8*)(lrow + r_off[0]);
      pa1.s = *(const s16x8*)(lrow + r_off[1]);
      oacc[g][0] = __builtin_amdgcn_mfma_f32_16x16x32_bf16(pa0.v, vb[0][0].v, oacc[g][0], 0, 0, 0);
      oacc[g][1] = __builtin_amdgcn_mfma_f32_16x16x32_bf16(pa0.v, vb[0][1].v, oacc[g][1], 0, 0, 0);
      lacc[g]    = __builtin_amdgcn_mfma_f32_16x16x32_bf16(pa0.v, ones.v,     lacc[g],    0, 0, 0);
      oacc[g][0] = __builtin_amdgcn_mfma_f32_16x16x32_bf16(pa1.v, vb[1][0].v, oacc[g][0], 0, 0, 0);
      oacc[g][1] = __builtin_amdgcn_mfma_f32_16x16x32_bf16(pa1.v, vb[1][1].v, oacc[g][1], 0, 0, 0);
      lacc[g]    = __builtin_amdgcn_mfma_f32_16x16x32_bf16(pa1.v, ones.v,     lacc[g],    0, 0, 0);
    }
    __builtin_amdgcn_s_setprio(0);
    // ---- write prefetched tile to the other buffer ----
    if (it < 15) {
      *(s16x8*)(&Kl[buf ^ 1][kdst]) = pk;
      *(s16x8*)(&Vl[buf ^ 1][vdst]) = pv;
      if (tid < 16) *(f32x4*)(&Cf[buf ^ 1][tid * 4]) = pc;
    }
    __syncthreads();
  }

#pragma unroll
  for (int g = 0; g < 2; ++g) {
#pragma unroll
    for (int r = 0; r < 4; ++r) {
      float inv = 1.0f / lacc[g][r];
      int q = qbase + g * 16 + lg * 4 + r;
      xat[(size_t)(b * 2048 + q) * 256 + h * 32 + lc] = f2bf(oacc[g][0][r] * inv);
      xat[(size_t)(b * 2048 + q) * 256 + h * 32 + 16 + lc] = f2bf(oacc[g][1][r] * inv);
    }
  }
}

// ---------------- launch ----------------

extern "C" void kernel_launch(void* const* d_in, const int* in_sizes, int n_in,
                              void* d_out, int out_size, void* d_ws, size_t ws_size,
                              hipStream_t stream) {
  (void)in_sizes; (void)n_in; (void)out_size; (void)ws_size;
  const float* q_x         = (const float*)d_in[0];
  const float* kv_x        = (const float*)d_in[1];
  const float* token_score = (const float*)d_in[2];
  const int*   idx_token   = (const int*)d_in[3];
  const float* q_w         = (const float*)d_in[4];
  const float* kv_w        = (const float*)d_in[5];
  const float* proj_w      = (const float*)d_in[6];
  const float* proj_b      = (const float*)d_in[7];
  const float* sr_w        = (const float*)d_in[8];
  const float* sr_b        = (const float*)d_in[9];
  const float* ln_w        = (const float*)d_in[10];
  const float* ln_b        = (const float*)d_in[11];
  float* out = (float*)d_out;

  char* ws = (char*)d_ws;
  unsigned short* q_s   = (unsigned short*)(ws + 0);          // 64*2048*32  bf16 = 8 MB
  unsigned short* xat   = (unsigned short*)(ws + 8388608);    // 16384*256   bf16 = 8 MB
  unsigned short* w4t   = (unsigned short*)(ws + 25165824);   // 256*1024    bf16
  unsigned short* kv_ln = (unsigned short*)(ws + 25690112);   // 8192*256    bf16
  unsigned short* kmat  = (unsigned short*)(ws + 29884416);   // 64*1024*32  bf16
  unsigned short* vt    = (unsigned short*)(ws + 34078720);   // 64*32*1024  bf16
  float*          confp = (float*)(ws + 38273024);            // 8*1024      f32
  unsigned short* q_wb  = (unsigned short*)(ws + 46694400);   // 256*256     bf16
  unsigned short* kv_wb = (unsigned short*)(ws + 46825472);   // 512*256     bf16
  unsigned short* p_wb  = (unsigned short*)(ws + 47087616);   // 256*256     bf16

  k_pre<<<dim3(2080), dim3(256), 0, stream>>>(q_w, kv_w, proj_w, sr_w, token_score, idx_token,
                                              q_wb, kv_wb, p_wb, w4t, confp);
  k_qc<<<dim3(768), dim3(256), 0, stream>>>(q_x, q_wb, q_s, kv_x, idx_token, w4t,
                                            sr_b, ln_w, ln_b, kv_ln);
  k_kvproj<<<dim3(512), dim3(256), 0, stream>>>(kv_ln, kv_wb, kmat, vt);
  k_attn<<<dim3(1024), dim3(256), 0, stream>>>(q_s, kmat, vt, confp, xat);
  k_proj<<<dim3(512), dim3(256), 0, stream>>>(xat, p_wb, proj_b, out);
}